// Round 11
// baseline (268.239 us; speedup 1.0000x reference)
//
#include <hip/hip_runtime.h>

#define NX 1024
#define NT 64
#define NBATCH 16
#define NBPB 16          // blocks per batch (64 cells each)
#define NBLK (NBATCH * NBPB)
#define DXC 0.02f
#define INV_SIG 20.0f
#define BIGF 1.0e6f

typedef __attribute__((ext_vector_type(8))) short bf16x8;
typedef __attribute__((ext_vector_type(4))) float f32x4;
typedef unsigned long long u64t;

// round-to-nearest-even f32 -> bf16
__device__ __forceinline__ unsigned short f2bf(float x) {
    unsigned u = __builtin_bit_cast(unsigned, x);
    u += 0x7FFFu + ((u >> 16) & 1u);
    return (unsigned short)(u >> 16);
}
__device__ __forceinline__ float bf2f(unsigned short h) {
    return __builtin_bit_cast(float, (unsigned)h << 16);
}
// HW packed f32x2 -> bf16x2 (lo = src0, hi = src1)
__device__ __forceinline__ unsigned cvt_pk_bf16(float lo, float hi) {
    unsigned r;
    asm("v_cvt_pk_bf16_f32 %0, %1, %2" : "=v"(r) : "v"(lo), "v"(hi));
    return r;
}

// Exact-GELU via Abramowitz-Stegun 7.1.26 erf (|err| <= 1.5e-7).
__device__ __forceinline__ float fast_gelu(float x) {
    float z = fabsf(x) * 0.70710678118654752f;
    float t = __builtin_amdgcn_rcpf(fmaf(0.3275911f, z, 1.0f));
    float p = fmaf(t, 1.061405429f, -1.453152027f);
    p = fmaf(t, p, 1.421413741f);
    p = fmaf(t, p, -0.284496736f);
    p = fmaf(t, p, 0.254829592f);
    p = p * t;
    float e = __expf(-z * z);
    float erf_abs = fmaf(-p, e, 1.0f);
    return 0.5f * x * (1.0f + copysignf(erf_abs, x));
}

// SYSTEM-scope relaxed (L3 coherence point; no cache inv/wb) — cross-XCD safe.
__device__ __forceinline__ u64t sys_load_u64(const u64t* p) {
    return __hip_atomic_load(p, __ATOMIC_RELAXED, __HIP_MEMORY_SCOPE_SYSTEM);
}
__device__ __forceinline__ void sys_store_u64(u64t* p, u64t v) {
    __hip_atomic_store(p, v, __ATOMIC_RELAXED, __HIP_MEMORY_SCOPE_SYSTEM);
}

// XOR-swizzled [64][64] bf16 LDS layout: 16B chunk index XOR'd with row&7.
__device__ __forceinline__ int swz(int row, int k) {
    return (row << 6) + ((((k >> 3) ^ row) & 7) << 3) + (k & 7);
}

__global__ void __launch_bounds__(1024, 1) nfv_kernel(
    const float* __restrict__ grid, const float* __restrict__ dtp,
    const float* __restrict__ W0, const float* __restrict__ b0,
    const float* __restrict__ W1, const float* __restrict__ b1,
    const float* __restrict__ W2, const float* __restrict__ b2,
    const float* __restrict__ W3, const float* __restrict__ b3,
    float* __restrict__ outp, u64t* __restrict__ halo)
{
    __shared__ float st_s[128];     // state strip, global [c0-32, c0+96)
    __shared__ __align__(16) unsigned short feat_s[64 * 64]; // bf16 features, swz
    __shared__ __align__(16) unsigned short w0s[64 * 64];    // bf16 W0' (K<32), swz
    __shared__ __align__(16) unsigned short actA[64 * 64];
    __shared__ __align__(16) unsigned short actB[64 * 64];
    __shared__ __align__(16) unsigned short w1s[64 * 64];
    __shared__ __align__(16) unsigned short w2s[64 * 64];
    __shared__ float bias0_s[64], bias1_s[64], bias2_s[64], w3_s[64];
    __shared__ __align__(16) float part_s[64 * 4];           // L3 partials [row][tn]

    const int tid  = threadIdx.x;
    const int lane = tid & 63;
    const int wid  = tid >> 6;
    const int bid  = blockIdx.x;
    const int b    = bid >> 4;            // batch
    const int bb   = bid & 15;            // block within batch
    const int c0   = bb * 64;
    const float dtv = dtp[b];
    const float r   = dtv / DXC;
    const float b3v = b3[0];

    const float* grow = grid + (size_t)b * (NT * NX);
    float*       orow = outp + (size_t)b * (NT * NX);

    // ---- prologue: weights -> swizzled bf16 LDS ----
    for (int e = tid; e < 4096; e += 1024) {
        int o = e >> 6, i = e & 63;
        w1s[swz(o, i)] = f2bf(W1[e]);
        w2s[swz(o, i)] = f2bf(W2[e]);
    }
    // L0 refactor: W0[:,k]*s + W0[:,7+k]*(1-2s) = A_k*s + W0[:,7+k],
    //   A_k = W0[:,k] - 2*W0[:,7+k].  Slot k: A_k (s_hi), slot 7+k: A_k (s_lo),
    //   slots 14..20: prox weights, 21: dt weight, 22..31: zero pad.
    for (int e = tid; e < 2048; e += 1024) {
        int o = e >> 5, i = e & 31;
        float wv;
        if (i < 7)       wv = W0[o * 22 + i] - 2.0f * W0[o * 22 + 7 + i];
        else if (i < 14) wv = W0[o * 22 + (i - 7)] - 2.0f * W0[o * 22 + i];
        else if (i < 22) wv = W0[o * 22 + i];
        else             wv = 0.0f;
        w0s[swz(o, i)] = f2bf(wv);
    }
    ((unsigned*)feat_s)[tid]        = 0;   // zero all 4096 bf16 entries
    ((unsigned*)feat_s)[tid + 1024] = 0;   // (pad K slots stay 0 forever)
    if (tid < 64) {
        float bb0 = b0[tid];
        #pragma unroll
        for (int k = 7; k < 14; ++k) bb0 += W0[tid * 22 + k];  // char constant fold
        bias0_s[tid] = bb0;
        bias1_s[tid] = b1[tid];
        bias2_s[tid] = b2[tid];
        w3_s[tid]    = W3[tid];
        orow[c0 + tid] = grow[c0 + tid];   // t = 0 output
    }
    if (wid == 0) {                        // initial strip (row 0), edge-clamped
        int ga = c0 - 32 + lane;  ga = ga < 0 ? 0 : ga;
        int gb = c0 + 32 + lane;  gb = gb > NX - 1 ? NX - 1 : gb;
        st_s[lane]      = grow[ga];
        st_s[lane + 64] = grow[gb];
    }

    // fragment geometry (shared by L0/L1/L2)
    const int tm  = wid >> 2, tn = wid & 3;
    const int l15 = lane & 15;
    const int kb0 = lane >> 4;                   // 16B-chunk idx: 0..3
    const int col = tn * 16 + l15;
    const int row0 = tm * 16 + ((lane >> 4) << 2);
    const int arow = tm * 16 + l15;
    const int brow = tn * 16 + l15;

    __syncthreads();   // A0: prologue + initial strip ready

    for (int t = 1; t < NT; ++t) {
        // ---- waves 0-7: ballot prox + feature build -> feat_s (st_s = row t-1) ----
        if (wid < 7) {
            bool p0 = st_s[lane + 1] > st_s[lane];
            int i2 = 65 + lane; if (i2 > 127) i2 = 127;
            bool p1 = (lane < 63) && (st_s[i2] > st_s[64 + lane]);
            u64t m0 = __ballot(p0);
            u64t m1 = __ballot(p1);

            // query cell: strip idx of stencil slot wid for row `lane`,
            // CLAMPED at batch-row edges (reference pads with mode='edge')
            int c = lane + 29 + wid;
            if (bb == 0      && c < 32) c = 32;
            if (bb == NBPB-1 && c > 95) c = 95;

            float dL = BIGF, dR = BIGF;
            u64t selhi = 0, sello;
            if (c >= 65) selhi = m1 & (((u64t)1 << (c - 64)) - 1);
            sello = (c <= 63) ? (m0 & (((u64t)1 << c) - 1)) : m0;
            if (selhi)      dL = (float)(c - (127 - __builtin_clzll(selhi))) - 0.5f;
            else if (sello) dL = (float)(c - (63  - __builtin_clzll(sello))) - 0.5f;
            if (c <= 63) {
                u64t r0 = m0 >> c;
                if (r0)      dR = (float)__builtin_ctzll(r0) + 0.5f;
                else if (m1) dR = (float)(64 - c + __builtin_ctzll(m1)) + 0.5f;
            } else {
                u64t r1 = m1 >> (c - 64);
                if (r1)      dR = (float)__builtin_ctzll(r1) + 0.5f;
            }
            float d = fminf(dL, dR);                    // in cell units
            float prox = __expf(-d * (DXC * INV_SIG));

            float sv = st_s[c];
            unsigned short shi = f2bf(sv);
            unsigned short slo = f2bf(sv - bf2f(shi));  // double-bf16 state
            feat_s[swz(lane, wid)]      = shi;
            feat_s[swz(lane, 7 + wid)]  = slo;
            feat_s[swz(lane, 14 + wid)] = f2bf(prox);
        } else if (wid == 7) {
            feat_s[swz(lane, 21)] = f2bf(dtv);
        }
        __syncthreads();   // B: features ready

        // ---- L0 (1x MFMA bf16, K=32): feat x W0'^T -> actA ----
        {
            f32x4 c4 = {0.0f, 0.0f, 0.0f, 0.0f};
            c4 = __builtin_amdgcn_mfma_f32_16x16x32_bf16(
                    *(const bf16x8*)(const void*)&feat_s[(arow << 6) + (((kb0 ^ arow) & 7) << 3)],
                    *(const bf16x8*)(const void*)&w0s   [(brow << 6) + (((kb0 ^ brow) & 7) << 3)], c4, 0, 0, 0);
            float bias = bias0_s[col];
            unsigned u01 = cvt_pk_bf16(fast_gelu(c4[0] + bias), fast_gelu(c4[1] + bias));
            unsigned u23 = cvt_pk_bf16(fast_gelu(c4[2] + bias), fast_gelu(c4[3] + bias));
            actA[swz(row0    , col)] = (unsigned short)u01;
            actA[swz(row0 + 1, col)] = (unsigned short)(u01 >> 16);
            actA[swz(row0 + 2, col)] = (unsigned short)u23;
            actA[swz(row0 + 3, col)] = (unsigned short)(u23 >> 16);
        }
        __syncthreads();   // C: actA ready

        // ---- L1 (MFMA bf16): actA x W1^T -> actB ----
        {
            f32x4 c4 = {0.0f, 0.0f, 0.0f, 0.0f};
            c4 = __builtin_amdgcn_mfma_f32_16x16x32_bf16(
                    *(const bf16x8*)(const void*)&actA[(arow << 6) + (((kb0     ^ arow) & 7) << 3)],
                    *(const bf16x8*)(const void*)&w1s [(brow << 6) + (((kb0     ^ brow) & 7) << 3)], c4, 0, 0, 0);
            c4 = __builtin_amdgcn_mfma_f32_16x16x32_bf16(
                    *(const bf16x8*)(const void*)&actA[(arow << 6) + ((((kb0+4) ^ arow) & 7) << 3)],
                    *(const bf16x8*)(const void*)&w1s [(brow << 6) + ((((kb0+4) ^ brow) & 7) << 3)], c4, 0, 0, 0);
            float bias = bias1_s[col];
            unsigned u01 = cvt_pk_bf16(fast_gelu(c4[0] + bias), fast_gelu(c4[1] + bias));
            unsigned u23 = cvt_pk_bf16(fast_gelu(c4[2] + bias), fast_gelu(c4[3] + bias));
            actB[swz(row0    , col)] = (unsigned short)u01;
            actB[swz(row0 + 1, col)] = (unsigned short)(u01 >> 16);
            actB[swz(row0 + 2, col)] = (unsigned short)u23;
            actB[swz(row0 + 3, col)] = (unsigned short)(u23 >> 16);
        }
        __syncthreads();   // D: actB ready

        // ---- L2 (MFMA bf16) + fused L3 partial (4-stage shfl -> f32x4/row) ----
        {
            f32x4 c4 = {0.0f, 0.0f, 0.0f, 0.0f};
            c4 = __builtin_amdgcn_mfma_f32_16x16x32_bf16(
                    *(const bf16x8*)(const void*)&actB[(arow << 6) + (((kb0     ^ arow) & 7) << 3)],
                    *(const bf16x8*)(const void*)&w2s [(brow << 6) + (((kb0     ^ brow) & 7) << 3)], c4, 0, 0, 0);
            c4 = __builtin_amdgcn_mfma_f32_16x16x32_bf16(
                    *(const bf16x8*)(const void*)&actB[(arow << 6) + ((((kb0+4) ^ arow) & 7) << 3)],
                    *(const bf16x8*)(const void*)&w2s [(brow << 6) + ((((kb0+4) ^ brow) & 7) << 3)], c4, 0, 0, 0);
            float bias = bias2_s[col];
            float w3c  = w3_s[col];
            #pragma unroll
            for (int j = 0; j < 4; ++j) {
                float p = w3c * fast_gelu(c4[j] + bias);
                p += __shfl_xor(p, 1);
                p += __shfl_xor(p, 2);
                p += __shfl_xor(p, 4);
                p += __shfl_xor(p, 8);
                if (l15 == 0)
                    part_s[(row0 + j) * 4 + tn] = p;   // one f32 per (row, tn)
            }
        }
        __syncthreads();   // E: partials ready

        // ---- E->A window: distributed update (waves 0,4,8,12) || poll (wave1) ----
        if ((wid & 3) == 0) {
            const int g   = wid >> 2;
            const int row = g * 16 + lane;            // lanes 0-15 active
            float ns = 0.0f;
            if (lane < 16) {
                f32x4 p4 = *(const f32x4*)(const void*)&part_s[row * 4];
                float sum = p4[0] + p4[1] + p4[2] + p4[3];
                ns = st_s[32 + row] + r * (sum + b3v);
                ns = fminf(1.0f, fmaxf(0.0f, ns));
                if (t < NT - 1) {
                    u64t u = ((u64t)(unsigned)t << 32) |
                             (u64t)(unsigned)__builtin_bit_cast(unsigned, ns);
                    sys_store_u64(&halo[(size_t)bid * 128 + (t & 1) * 64 + row], u);
                }
                orow[(size_t)t * NX + c0 + row] = ns;
                st_s[32 + row] = ns;
            }
            // edge blocks: updater wave itself fills the clamped halo (no race)
            if (bb == 0 && wid == 0 && t < NT - 1) {
                float e = __shfl(ns, 0);              // row 0 value
                if (lane >= 16 && lane < 48) st_s[lane - 16] = e;
            }
            if (bb == NBPB - 1 && wid == 12 && t < NT - 1) {
                float e = __shfl(ns, 15);             // row 63 value
                if (lane >= 16 && lane < 48) st_s[96 + (lane - 16)] = e;
            }
        } else if (wid == 1 && t < NT - 1) {
            // fill halo of row t from neighbors (fused data+tag, single RT)
            const unsigned need = (unsigned)t;
            const int p = t & 1;
            const int j = lane & 31;
            const bool left = lane < 32;
            const bool have = left ? (bb > 0) : (bb < NBPB - 1);
            if (have) {
                const u64t* src = left
                    ? &halo[(size_t)(bid - 1) * 128 + p * 64 + 32 + j]
                    : &halo[(size_t)(bid + 1) * 128 + p * 64 + j];
                u64t u;
                do { u = sys_load_u64(src); } while ((unsigned)(u >> 32) < need);
                st_s[left ? j : 96 + j] = __builtin_bit_cast(float, (unsigned)u);
            }
        }
        __syncthreads();   // A: row t strip complete; next iteration
    }
}

extern "C" void kernel_launch(void* const* d_in, const int* in_sizes, int n_in,
                              void* d_out, int out_size, void* d_ws, size_t ws_size,
                              hipStream_t stream) {
    const float* grid = (const float*)d_in[0];
    const float* dtp  = (const float*)d_in[1];
    const float* W0   = (const float*)d_in[2];
    const float* b0   = (const float*)d_in[3];
    const float* W1   = (const float*)d_in[4];
    const float* b1   = (const float*)d_in[5];
    const float* W2   = (const float*)d_in[6];
    const float* b2   = (const float*)d_in[7];
    const float* W3   = (const float*)d_in[8];
    const float* b3   = (const float*)d_in[9];
    float* outp = (float*)d_out;

    u64t* halo = (u64t*)d_ws;                     // NBLK * 128 u64 (256 KB)

    // zero the whole halo each launch: tags embedded in data words must not
    // leak across graph replays (stale tag >= need would hand out old rows)
    hipMemsetAsync(d_ws, 0, (size_t)NBLK * 128 * sizeof(u64t), stream);

    void* args[] = {(void*)&grid, (void*)&dtp, (void*)&W0, (void*)&b0,
                    (void*)&W1, (void*)&b1, (void*)&W2, (void*)&b2,
                    (void*)&W3, (void*)&b3, (void*)&outp, (void*)&halo};
    hipLaunchCooperativeKernel((const void*)nfv_kernel,
                               dim3(NBLK), dim3(1024), args, 0, stream);
}

// Round 13
// 231.883 us; speedup vs baseline: 1.1568x; 1.1568x over previous
//
#include <hip/hip_runtime.h>

#define NX 1024
#define NT 64
#define NBATCH 16
#define BPB 32           // blocks per batch chain (32 cells each)
#define NBLK (NBATCH * BPB)   // 512 = 256 CUs x 2 blocks
#define DXC 0.02f
#define INV_SIG 20.0f
#define BIGF 1.0e6f

typedef __attribute__((ext_vector_type(8))) short bf16x8;
typedef __attribute__((ext_vector_type(4))) float f32x4;
typedef unsigned long long u64t;

// round-to-nearest-even f32 -> bf16
__device__ __forceinline__ unsigned short f2bf(float x) {
    unsigned u = __builtin_bit_cast(unsigned, x);
    u += 0x7FFFu + ((u >> 16) & 1u);
    return (unsigned short)(u >> 16);
}
__device__ __forceinline__ float bf2f(unsigned short h) {
    return __builtin_bit_cast(float, (unsigned)h << 16);
}
// HW packed f32x2 -> bf16x2 (lo = src0, hi = src1)
__device__ __forceinline__ unsigned cvt_pk_bf16(float lo, float hi) {
    unsigned r;
    asm("v_cvt_pk_bf16_f32 %0, %1, %2" : "=v"(r) : "v"(lo), "v"(hi));
    return r;
}

// Exact-GELU via Abramowitz-Stegun 7.1.26 erf (|err| <= 1.5e-7).
__device__ __forceinline__ float fast_gelu(float x) {
    float z = fabsf(x) * 0.70710678118654752f;
    float t = __builtin_amdgcn_rcpf(fmaf(0.3275911f, z, 1.0f));
    float p = fmaf(t, 1.061405429f, -1.453152027f);
    p = fmaf(t, p, 1.421413741f);
    p = fmaf(t, p, -0.284496736f);
    p = fmaf(t, p, 0.254829592f);
    p = p * t;
    float e = __expf(-z * z);
    float erf_abs = fmaf(-p, e, 1.0f);
    return 0.5f * x * (1.0f + copysignf(erf_abs, x));
}

// SYSTEM-scope relaxed (L3 coherence point; no cache inv/wb) — cross-XCD safe.
__device__ __forceinline__ u64t sys_load_u64(const u64t* p) {
    return __hip_atomic_load(p, __ATOMIC_RELAXED, __HIP_MEMORY_SCOPE_SYSTEM);
}
__device__ __forceinline__ void sys_store_u64(u64t* p, u64t v) {
    __hip_atomic_store(p, v, __ATOMIC_RELAXED, __HIP_MEMORY_SCOPE_SYSTEM);
}

// XOR-swizzled [R][64] bf16 LDS layout: 16B chunk index XOR'd with row&7.
__device__ __forceinline__ int swz(int row, int k) {
    return (row << 6) + ((((k >> 3) ^ row) & 7) << 3) + (k & 7);
}

__global__ void __launch_bounds__(512, 4) nfv_kernel(
    const float* __restrict__ grid, const float* __restrict__ dtp,
    const float* __restrict__ W0, const float* __restrict__ b0,
    const float* __restrict__ W1, const float* __restrict__ b1,
    const float* __restrict__ W2, const float* __restrict__ b2,
    const float* __restrict__ W3, const float* __restrict__ b3,
    float* __restrict__ outp, u64t* __restrict__ halo)
{
    __shared__ float st_s[96];      // state strip, global [c0-32, c0+64)
    __shared__ __align__(16) unsigned short feat_s[32 * 64]; // bf16 features, swz
    __shared__ __align__(16) unsigned short actA[32 * 64];
    __shared__ __align__(16) unsigned short actB[32 * 64];
    __shared__ __align__(16) float part_s[32 * 20];          // [row][16 partials + pad]

    const int tid  = threadIdx.x;
    const int lane = tid & 63;
    const int wid  = tid >> 6;            // 0..7
    const int bid  = blockIdx.x;
    const int b    = bid >> 5;            // batch
    const int bb   = bid & 31;            // block within chain
    const int c0   = bb * 32;
    const float dtv = dtp[b];
    const float r   = dtv / DXC;
    const float b3v = b3[0];

    const float* grow = grid + (size_t)b * (NT * NX);
    float*       orow = outp + (size_t)b * (NT * NX);

    // fragment geometry (shared by L0/L1/L2): 8 waves = 2x4 tiles of 16x16
    const int tm  = wid >> 2, tn = wid & 3;
    const int l15 = lane & 15;
    const int kb0 = lane >> 4;                   // 16B-chunk idx: 0..3
    const int col = tn * 16 + l15;               // output channel (0..63)
    const int row0 = tm * 16 + ((lane >> 4) << 2);
    const int arow = tm * 16 + l15;              // feat/act row (0..31)

    // ---- prologue: per-lane constant weight fragments (registers, no LDS) ----
    // L0 refactor: W0[:,k]*s + W0[:,7+k]*(1-2s) = A_k*s + W0[:,7+k],
    //   A_k = W0[:,k]-2*W0[:,7+k]. Slot k: A_k (s_hi); slot 7+k: A_k (s_lo);
    //   slots 14..20: prox weights; 21: dt weight; 22..31: zero.
    bf16x8 w0f, w1fa, w1fb, w2fa, w2fb;
    {
        const int k0 = kb0 * 8;
        #pragma unroll
        for (int i = 0; i < 8; ++i) {
            int k = k0 + i;
            float wv;
            if (k < 7)       wv = W0[col * 22 + k] - 2.0f * W0[col * 22 + 7 + k];
            else if (k < 14) wv = W0[col * 22 + (k - 7)] - 2.0f * W0[col * 22 + k];
            else if (k < 22) wv = W0[col * 22 + k];
            else             wv = 0.0f;
            w0f[i]  = (short)f2bf(wv);
            w1fa[i] = (short)f2bf(W1[col * 64 + k0 + i]);
            w1fb[i] = (short)f2bf(W1[col * 64 + k0 + 32 + i]);
            w2fa[i] = (short)f2bf(W2[col * 64 + k0 + i]);
            w2fb[i] = (short)f2bf(W2[col * 64 + k0 + 32 + i]);
        }
    }
    float bias0 = b0[col];
    #pragma unroll
    for (int k = 7; k < 14; ++k) bias0 += W0[col * 22 + k];  // char constant fold
    const float bias1 = b1[col], bias2 = b2[col], w3c = W3[col];

    ((unsigned*)feat_s)[tid]       = 0;    // zero all 2048 bf16 entries
    ((unsigned*)feat_s)[tid + 512] = 0;    // (pad K slots stay 0 forever)
    if (tid < 32) {
        orow[c0 + tid] = grow[c0 + tid];   // t = 0 output
        feat_s[swz(tid, 21)] = f2bf(dtv);  // dt slot: constant, write once
    }
    if (tid < 96) {                        // initial strip (row 0), edge-clamped
        int ga = c0 - 32 + tid;
        ga = ga < 0 ? 0 : (ga > NX - 1 ? NX - 1 : ga);
        st_s[tid] = grow[ga];
    }

    for (int t = 1; t < NT; ++t) {
        // ---- wave0: fill strip halo for row t-1 (single-RT fused data+tag) ----
        if (wid == 0 && t >= 2) {
            const unsigned need = (unsigned)(t - 1);
            const int p = (t - 1) & 1;
            const bool left = lane < 32;
            const int j = lane & 31;
            const bool have = left ? (bb > 0) : (bb < BPB - 1);
            if (have) {
                const u64t* src = left
                    ? &halo[(size_t)(bid - 1) * 64 + p * 32 + j]
                    : &halo[(size_t)(bid + 1) * 64 + p * 32 + j];
                u64t u;
                do { u = sys_load_u64(src); } while ((unsigned)(u >> 32) < need);
                st_s[left ? j : 64 + j] = __builtin_bit_cast(float, (unsigned)u);
            }
        }
        __syncthreads();   // A: strip (row t-1) complete (covers prologue @ t=1)

        // ---- waves 0-6: ballot prox + features (lanes 0-31) ----
        if (wid < 7) {
            // shock ballots over strip pairs p=0..94 (pair p: cells p,p+1)
            bool q0 = st_s[lane + 1] > st_s[lane];               // pairs 0..63
            bool q1 = (lane < 31) && (st_s[65 + lane] > st_s[64 + lane]);
            u64t m0 = __ballot(q0);
            u64t m1 = __ballot(q1);
            if (lane < 32) {
                const int row = lane;
                // query cell: strip idx of stencil slot wid; edge-clamped
                int c = row + 29 + wid;
                if (bb == 0       && c < 32) c = 32;
                if (bb == BPB - 1 && c > 63) c = 63;

                float dL = BIGF, dR = BIGF;
                u64t selhi = 0, sello;
                if (c >= 65) selhi = m1 & (((u64t)1 << (c - 64)) - 1);
                sello = (c <= 63) ? (m0 & (((u64t)1 << c) - 1)) : m0;
                if (selhi)      dL = (float)(c - (127 - __builtin_clzll(selhi))) - 0.5f;
                else if (sello) dL = (float)(c - (63  - __builtin_clzll(sello))) - 0.5f;
                if (c <= 63) {
                    u64t r0 = m0 >> c;
                    if (r0)      dR = (float)__builtin_ctzll(r0) + 0.5f;
                    else if (m1) dR = (float)(64 - c + __builtin_ctzll(m1)) + 0.5f;
                } else {
                    u64t r1 = m1 >> (c - 64);
                    if (r1)      dR = (float)__builtin_ctzll(r1) + 0.5f;
                }
                float d = fminf(dL, dR);                    // in cell units
                float prox = __expf(-d * (DXC * INV_SIG));

                float sv = st_s[c];
                unsigned short shi = f2bf(sv);
                unsigned short slo = f2bf(sv - bf2f(shi));  // double-bf16 state
                feat_s[swz(row, wid)]      = shi;
                feat_s[swz(row, 7 + wid)]  = slo;
                feat_s[swz(row, 14 + wid)] = f2bf(prox);
            }
        }
        __syncthreads();   // B: features ready

        // ---- L0 (1x MFMA bf16, K=32): feat x W0'^T -> actA ----
        {
            f32x4 c4 = {0.0f, 0.0f, 0.0f, 0.0f};
            c4 = __builtin_amdgcn_mfma_f32_16x16x32_bf16(
                    *(const bf16x8*)(const void*)&feat_s[(arow << 6) + (((kb0 ^ arow) & 7) << 3)],
                    w0f, c4, 0, 0, 0);
            unsigned u01 = cvt_pk_bf16(fast_gelu(c4[0] + bias0), fast_gelu(c4[1] + bias0));
            unsigned u23 = cvt_pk_bf16(fast_gelu(c4[2] + bias0), fast_gelu(c4[3] + bias0));
            actA[swz(row0    , col)] = (unsigned short)u01;
            actA[swz(row0 + 1, col)] = (unsigned short)(u01 >> 16);
            actA[swz(row0 + 2, col)] = (unsigned short)u23;
            actA[swz(row0 + 3, col)] = (unsigned short)(u23 >> 16);
        }
        __syncthreads();   // C: actA ready

        // ---- L1 (MFMA bf16, K=64): actA x W1^T -> actB ----
        {
            f32x4 c4 = {0.0f, 0.0f, 0.0f, 0.0f};
            c4 = __builtin_amdgcn_mfma_f32_16x16x32_bf16(
                    *(const bf16x8*)(const void*)&actA[(arow << 6) + (((kb0     ^ arow) & 7) << 3)],
                    w1fa, c4, 0, 0, 0);
            c4 = __builtin_amdgcn_mfma_f32_16x16x32_bf16(
                    *(const bf16x8*)(const void*)&actA[(arow << 6) + ((((kb0+4) ^ arow) & 7) << 3)],
                    w1fb, c4, 0, 0, 0);
            unsigned u01 = cvt_pk_bf16(fast_gelu(c4[0] + bias1), fast_gelu(c4[1] + bias1));
            unsigned u23 = cvt_pk_bf16(fast_gelu(c4[2] + bias1), fast_gelu(c4[3] + bias1));
            actB[swz(row0    , col)] = (unsigned short)u01;
            actB[swz(row0 + 1, col)] = (unsigned short)(u01 >> 16);
            actB[swz(row0 + 2, col)] = (unsigned short)u23;
            actB[swz(row0 + 3, col)] = (unsigned short)(u23 >> 16);
        }
        __syncthreads();   // D: actB ready

        // ---- L2 (MFMA bf16) + fused L3 partial (2-stage shfl -> 16/row) ----
        {
            f32x4 c4 = {0.0f, 0.0f, 0.0f, 0.0f};
            c4 = __builtin_amdgcn_mfma_f32_16x16x32_bf16(
                    *(const bf16x8*)(const void*)&actB[(arow << 6) + (((kb0     ^ arow) & 7) << 3)],
                    w2fa, c4, 0, 0, 0);
            c4 = __builtin_amdgcn_mfma_f32_16x16x32_bf16(
                    *(const bf16x8*)(const void*)&actB[(arow << 6) + ((((kb0+4) ^ arow) & 7) << 3)],
                    w2fb, c4, 0, 0, 0);
            #pragma unroll
            for (int j = 0; j < 4; ++j) {
                float p = w3c * fast_gelu(c4[j] + bias2);
                p += __shfl_xor(p, 1);
                p += __shfl_xor(p, 2);
                if ((l15 & 3) == 0)
                    part_s[(row0 + j) * 20 + (tn << 2) + (l15 >> 2)] = p;
            }
        }
        __syncthreads();   // E: partials ready

        // ---- wave0: update + publish + store (+ edge-halo fill) ----
        if (wid == 0) {
            float ns = 0.0f;
            if (lane < 32) {
                const int row = lane;
                const f32x4* pr = (const f32x4*)(const void*)&part_s[row * 20];
                f32x4 s4 = pr[0] + pr[1] + pr[2] + pr[3];
                float sum = s4[0] + s4[1] + s4[2] + s4[3];
                ns = st_s[32 + row] + r * (sum + b3v);
                ns = fminf(1.0f, fmaxf(0.0f, ns));
                if (t < NT - 1) {
                    u64t u = ((u64t)(unsigned)t << 32) |
                             (u64t)(unsigned)__builtin_bit_cast(unsigned, ns);
                    sys_store_u64(&halo[(size_t)bid * 64 + (t & 1) * 32 + row], u);
                }
                orow[(size_t)t * NX + c0 + row] = ns;
                st_s[32 + row] = ns;
            }
            // edge blocks: fill clamped halo for next step (lanes 32-63)
            if (bb == 0 && t < NT - 1) {
                float e = __shfl(ns, 0);               // row 0 value
                if (lane >= 32) st_s[lane - 32] = e;
            }
            if (bb == BPB - 1 && t < NT - 1) {
                float e = __shfl(ns, 31);              // row 31 value
                if (lane >= 32) st_s[64 + (lane - 32)] = e;
            }
        }
        // next iter's barrier A guards st_s/feat_s/actA/part_s reuse
    }
}

extern "C" void kernel_launch(void* const* d_in, const int* in_sizes, int n_in,
                              void* d_out, int out_size, void* d_ws, size_t ws_size,
                              hipStream_t stream) {
    const float* grid = (const float*)d_in[0];
    const float* dtp  = (const float*)d_in[1];
    const float* W0   = (const float*)d_in[2];
    const float* b0   = (const float*)d_in[3];
    const float* W1   = (const float*)d_in[4];
    const float* b1   = (const float*)d_in[5];
    const float* W2   = (const float*)d_in[6];
    const float* b2   = (const float*)d_in[7];
    const float* W3   = (const float*)d_in[8];
    const float* b3   = (const float*)d_in[9];
    float* outp = (float*)d_out;

    u64t* halo = (u64t*)d_ws;                     // NBLK * 64 u64 (256 KB)

    // zero the whole halo each launch: tags embedded in data words must not
    // leak across graph replays (stale tag >= need would hand out old rows)
    hipMemsetAsync(d_ws, 0, (size_t)NBLK * 64 * sizeof(u64t), stream);

    void* args[] = {(void*)&grid, (void*)&dtp, (void*)&W0, (void*)&b0,
                    (void*)&W1, (void*)&b1, (void*)&W2, (void*)&b2,
                    (void*)&W3, (void*)&b3, (void*)&outp, (void*)&halo};

    // Deterministic launch-mode choice (query enqueues nothing; capture-safe).
    // Coop launch caps grid at occupancy*256; if the calculator says <2
    // blocks/CU, fall back to a plain launch — all 512 blocks still fit
    // simultaneously (15.2KB LDS, 512 thr, VGPR bounded), so spins stay live.
    int maxb = 0;
    hipError_t qe = hipOccupancyMaxActiveBlocksPerMultiprocessor(
        &maxb, (const void*)nfv_kernel, 512, 0);
    if (qe == hipSuccess && maxb >= 2) {
        hipLaunchCooperativeKernel((const void*)nfv_kernel,
                                   dim3(NBLK), dim3(512), args, 0, stream);
    } else {
        hipLaunchKernelGGL(nfv_kernel, dim3(NBLK), dim3(512), 0, stream,
                           grid, dtp, W0, b0, W1, b1, W2, b2, W3, b3,
                           outp, halo);
    }
}

// Round 14
// 220.606 us; speedup vs baseline: 1.2159x; 1.0511x over previous
//
#include <hip/hip_runtime.h>

#define NX 1024
#define NT 64
#define NBATCH 16
#define BPB 64           // blocks per batch chain (16 cells each)
#define NBLK (NBATCH * BPB)   // 1024 = 256 CUs x 4 blocks
#define DXC 0.02f
#define INV_SIG 20.0f
#define BIGF 1.0e6f

typedef __attribute__((ext_vector_type(8))) short bf16x8;
typedef __attribute__((ext_vector_type(4))) float f32x4;
typedef unsigned long long u64t;

// round-to-nearest-even f32 -> bf16
__device__ __forceinline__ unsigned short f2bf(float x) {
    unsigned u = __builtin_bit_cast(unsigned, x);
    u += 0x7FFFu + ((u >> 16) & 1u);
    return (unsigned short)(u >> 16);
}
__device__ __forceinline__ float bf2f(unsigned short h) {
    return __builtin_bit_cast(float, (unsigned)h << 16);
}
// HW packed f32x2 -> bf16x2 (lo = src0, hi = src1)
__device__ __forceinline__ unsigned cvt_pk_bf16(float lo, float hi) {
    unsigned r;
    asm("v_cvt_pk_bf16_f32 %0, %1, %2" : "=v"(r) : "v"(lo), "v"(hi));
    return r;
}

// Exact-GELU via Abramowitz-Stegun 7.1.26 erf (|err| <= 1.5e-7).
__device__ __forceinline__ float fast_gelu(float x) {
    float z = fabsf(x) * 0.70710678118654752f;
    float t = __builtin_amdgcn_rcpf(fmaf(0.3275911f, z, 1.0f));
    float p = fmaf(t, 1.061405429f, -1.453152027f);
    p = fmaf(t, p, 1.421413741f);
    p = fmaf(t, p, -0.284496736f);
    p = fmaf(t, p, 0.254829592f);
    p = p * t;
    float e = __expf(-z * z);
    float erf_abs = fmaf(-p, e, 1.0f);
    return 0.5f * x * (1.0f + copysignf(erf_abs, x));
}

// SYSTEM-scope relaxed (L3 coherence point; no cache inv/wb) — cross-XCD safe.
__device__ __forceinline__ u64t sys_load_u64(const u64t* p) {
    return __hip_atomic_load(p, __ATOMIC_RELAXED, __HIP_MEMORY_SCOPE_SYSTEM);
}
__device__ __forceinline__ void sys_store_u64(u64t* p, u64t v) {
    __hip_atomic_store(p, v, __ATOMIC_RELAXED, __HIP_MEMORY_SCOPE_SYSTEM);
}

// XOR-swizzled [R][64] bf16 LDS layout: 16B chunk index XOR'd with row&7.
__device__ __forceinline__ int swz(int row, int k) {
    return (row << 6) + ((((k >> 3) ^ row) & 7) << 3) + (k & 7);
}

__global__ void __launch_bounds__(256, 4) nfv_kernel(
    const float* __restrict__ grid, const float* __restrict__ dtp,
    const float* __restrict__ W0, const float* __restrict__ b0,
    const float* __restrict__ W1, const float* __restrict__ b1,
    const float* __restrict__ W2, const float* __restrict__ b2,
    const float* __restrict__ W3, const float* __restrict__ b3,
    float* __restrict__ outp, u64t* __restrict__ halo)
{
    __shared__ float st_s[80];      // state strip, global [c0-32, c0+48)
    __shared__ __align__(16) unsigned short feat_s[16 * 64]; // bf16 features, swz
    __shared__ __align__(16) unsigned short actA[16 * 64];
    __shared__ __align__(16) unsigned short actB[16 * 64];
    __shared__ __align__(16) float part_s[16 * 20];          // [row][16 partials + pad]

    const int tid  = threadIdx.x;
    const int lane = tid & 63;
    const int wid  = tid >> 6;            // 0..3
    const int bid  = blockIdx.x;
    const int b    = bid >> 6;            // batch
    const int bb   = bid & 63;            // block within chain
    const int c0   = bb * 16;
    const float dtv = dtp[b];
    const float r   = dtv / DXC;
    const float b3v = b3[0];

    const float* grow = grid + (size_t)b * (NT * NX);
    float*       orow = outp + (size_t)b * (NT * NX);

    // fragment geometry: 4 waves = 1x4 tiles of 16x16 (M=16 cells, N=64 ch)
    const int l15 = lane & 15;
    const int kb0 = lane >> 4;                   // 16B-chunk idx: 0..3
    const int col = wid * 16 + l15;              // output channel (0..63)
    const int row0 = (lane >> 4) << 2;           // C rows: 0,4,8,12 (+j)
    const int arow = l15;                        // feat/act row (0..15)

    // ---- prologue: per-lane constant weight fragments (registers) ----
    // L0 refactor: W0[:,k]*s + W0[:,7+k]*(1-2s) = A_k*s + W0[:,7+k],
    //   A_k = W0[:,k]-2*W0[:,7+k]. Slot k: A_k (s_hi); slot 7+k: A_k (s_lo);
    //   slots 14..20: prox weights; 21: dt weight; 22..31: zero.
    bf16x8 w0f, w1fa, w1fb, w2fa, w2fb;
    {
        const int k0 = kb0 * 8;
        #pragma unroll
        for (int i = 0; i < 8; ++i) {
            int k = k0 + i;
            float wv;
            if (k < 7)       wv = W0[col * 22 + k] - 2.0f * W0[col * 22 + 7 + k];
            else if (k < 14) wv = W0[col * 22 + (k - 7)] - 2.0f * W0[col * 22 + k];
            else if (k < 22) wv = W0[col * 22 + k];
            else             wv = 0.0f;
            w0f[i]  = (short)f2bf(wv);
            w1fa[i] = (short)f2bf(W1[col * 64 + k0 + i]);
            w1fb[i] = (short)f2bf(W1[col * 64 + k0 + 32 + i]);
            w2fa[i] = (short)f2bf(W2[col * 64 + k0 + i]);
            w2fb[i] = (short)f2bf(W2[col * 64 + k0 + 32 + i]);
        }
    }
    float bias0 = b0[col];
    #pragma unroll
    for (int k = 7; k < 14; ++k) bias0 += W0[col * 22 + k];  // char constant fold
    const float bias1 = b1[col], bias2 = b2[col], w3c = W3[col];

    ((unsigned*)feat_s)[tid]       = 0;    // zero all 1024 bf16 entries
    ((unsigned*)feat_s)[tid + 256] = 0;    // (pad K slots stay 0 forever)
    if (tid < 16) {
        orow[c0 + tid] = grow[c0 + tid];   // t = 0 output
        feat_s[swz(tid, 21)] = f2bf(dtv);  // dt slot: constant, write once
    }
    if (tid < 80) {                        // initial strip (row 0), edge-clamped
        int ga = c0 - 32 + tid;
        ga = ga < 0 ? 0 : (ga > NX - 1 ? NX - 1 : ga);
        st_s[tid] = grow[ga];
    }

    for (int t = 1; t < NT; ++t) {
        // ---- wave0: fill 64 halo cells for row t-1 (fused data+tag/lane) ----
        // left: strip[0..31] <- globals [c0-32, c0); right: strip[48..79] <-
        // [c0+16, c0+48). Sources span bb-2..bb+2 (clamped); lane spins on its
        // own source word. Mailbox depth 4 (t&3): distance-2 skew <= 2 safe.
        if (wid == 0 && t >= 2) {
            const unsigned need = (unsigned)(t - 1);
            const int slot = (t - 1) & 3;
            int g = (lane < 32) ? (c0 - 32 + lane) : (c0 - 16 + lane);
            g = g < 0 ? 0 : (g > NX - 1 ? NX - 1 : g);
            const int src_bid = b * BPB + (g >> 4);
            const u64t* src = &halo[(size_t)src_bid * 64 + slot * 16 + (g & 15)];
            u64t u;
            do { u = sys_load_u64(src); } while ((unsigned)(u >> 32) < need);
            st_s[(lane < 32) ? lane : lane + 16] =
                __builtin_bit_cast(float, (unsigned)u);
        }
        __syncthreads();   // A: strip (row t-1) complete (covers prologue @t=1)

        // ---- all waves: ballot prox + features; slot s = wid*2+(lane>>5) ----
        {
            // shock ballots over strip pairs p=0..78 (pair p: cells p,p+1)
            bool q0 = st_s[lane + 1] > st_s[lane];               // pairs 0..63
            bool q1 = (lane < 15) && (st_s[65 + lane] > st_s[64 + lane]);
            u64t m0 = __ballot(q0);
            u64t m1 = __ballot(q1);
            const int s = wid * 2 + (lane >> 5);
            if (s < 7 && (lane & 31) < 16) {
                const int row = lane & 15;
                // query cell: strip idx of stencil slot s; edge-clamped
                int c = row + 29 + s;                   // in [29, 50] — always <64
                if (bb == 0       && c < 32) c = 32;
                if (bb == BPB - 1 && c > 47) c = 47;

                float dL = BIGF, dR = BIGF;
                u64t sello = m0 & (((u64t)1 << c) - 1); // pairs <= c-1
                if (sello) dL = (float)(c - (63 - __builtin_clzll(sello))) - 0.5f;
                u64t r0 = m0 >> c;                      // pairs >= c
                if (r0)      dR = (float)__builtin_ctzll(r0) + 0.5f;
                else if (m1) dR = (float)(64 - c + __builtin_ctzll(m1)) + 0.5f;
                float d = fminf(dL, dR);                // in cell units
                float prox = __expf(-d * (DXC * INV_SIG));

                float sv = st_s[c];
                unsigned short shi = f2bf(sv);
                unsigned short slo = f2bf(sv - bf2f(shi));  // double-bf16 state
                feat_s[swz(row, s)]      = shi;
                feat_s[swz(row, 7 + s)]  = slo;
                feat_s[swz(row, 14 + s)] = f2bf(prox);
            }
        }
        __syncthreads();   // B: features ready

        // ---- L0 (1x MFMA bf16, K=32): feat x W0'^T -> actA ----
        {
            f32x4 c4 = {0.0f, 0.0f, 0.0f, 0.0f};
            c4 = __builtin_amdgcn_mfma_f32_16x16x32_bf16(
                    *(const bf16x8*)(const void*)&feat_s[(arow << 6) + (((kb0 ^ arow) & 7) << 3)],
                    w0f, c4, 0, 0, 0);
            unsigned u01 = cvt_pk_bf16(fast_gelu(c4[0] + bias0), fast_gelu(c4[1] + bias0));
            unsigned u23 = cvt_pk_bf16(fast_gelu(c4[2] + bias0), fast_gelu(c4[3] + bias0));
            actA[swz(row0    , col)] = (unsigned short)u01;
            actA[swz(row0 + 1, col)] = (unsigned short)(u01 >> 16);
            actA[swz(row0 + 2, col)] = (unsigned short)u23;
            actA[swz(row0 + 3, col)] = (unsigned short)(u23 >> 16);
        }
        __syncthreads();   // C: actA ready

        // ---- L1 (MFMA bf16, K=64): actA x W1^T -> actB ----
        {
            f32x4 c4 = {0.0f, 0.0f, 0.0f, 0.0f};
            c4 = __builtin_amdgcn_mfma_f32_16x16x32_bf16(
                    *(const bf16x8*)(const void*)&actA[(arow << 6) + (((kb0     ^ arow) & 7) << 3)],
                    w1fa, c4, 0, 0, 0);
            c4 = __builtin_amdgcn_mfma_f32_16x16x32_bf16(
                    *(const bf16x8*)(const void*)&actA[(arow << 6) + ((((kb0+4) ^ arow) & 7) << 3)],
                    w1fb, c4, 0, 0, 0);
            unsigned u01 = cvt_pk_bf16(fast_gelu(c4[0] + bias1), fast_gelu(c4[1] + bias1));
            unsigned u23 = cvt_pk_bf16(fast_gelu(c4[2] + bias1), fast_gelu(c4[3] + bias1));
            actB[swz(row0    , col)] = (unsigned short)u01;
            actB[swz(row0 + 1, col)] = (unsigned short)(u01 >> 16);
            actB[swz(row0 + 2, col)] = (unsigned short)u23;
            actB[swz(row0 + 3, col)] = (unsigned short)(u23 >> 16);
        }
        __syncthreads();   // D: actB ready

        // ---- L2 (MFMA bf16) + fused L3 partial (2-stage shfl -> 16/row) ----
        {
            f32x4 c4 = {0.0f, 0.0f, 0.0f, 0.0f};
            c4 = __builtin_amdgcn_mfma_f32_16x16x32_bf16(
                    *(const bf16x8*)(const void*)&actB[(arow << 6) + (((kb0     ^ arow) & 7) << 3)],
                    w2fa, c4, 0, 0, 0);
            c4 = __builtin_amdgcn_mfma_f32_16x16x32_bf16(
                    *(const bf16x8*)(const void*)&actB[(arow << 6) + ((((kb0+4) ^ arow) & 7) << 3)],
                    w2fb, c4, 0, 0, 0);
            #pragma unroll
            for (int j = 0; j < 4; ++j) {
                float p = w3c * fast_gelu(c4[j] + bias2);
                p += __shfl_xor(p, 1);
                p += __shfl_xor(p, 2);
                if ((l15 & 3) == 0)
                    part_s[(row0 + j) * 20 + (wid << 2) + (l15 >> 2)] = p;
            }
        }
        __syncthreads();   // E: partials ready

        // ---- wave0: update + publish + store ----
        if (wid == 0 && lane < 16) {
            const int row = lane;
            const f32x4* pr = (const f32x4*)(const void*)&part_s[row * 20];
            f32x4 s4 = pr[0] + pr[1] + pr[2] + pr[3];
            float sum = s4[0] + s4[1] + s4[2] + s4[3];
            float ns = st_s[32 + row] + r * (sum + b3v);
            ns = fminf(1.0f, fmaxf(0.0f, ns));
            if (t < NT - 1) {
                u64t u = ((u64t)(unsigned)t << 32) |
                         (u64t)(unsigned)__builtin_bit_cast(unsigned, ns);
                sys_store_u64(&halo[(size_t)bid * 64 + (t & 3) * 16 + row], u);
            }
            orow[(size_t)t * NX + c0 + row] = ns;
            st_s[32 + row] = ns;
        }
        // next iter's barrier A guards st_s/feat_s/actA/part_s reuse
    }
}

extern "C" void kernel_launch(void* const* d_in, const int* in_sizes, int n_in,
                              void* d_out, int out_size, void* d_ws, size_t ws_size,
                              hipStream_t stream) {
    const float* grid = (const float*)d_in[0];
    const float* dtp  = (const float*)d_in[1];
    const float* W0   = (const float*)d_in[2];
    const float* b0   = (const float*)d_in[3];
    const float* W1   = (const float*)d_in[4];
    const float* b1   = (const float*)d_in[5];
    const float* W2   = (const float*)d_in[6];
    const float* b2   = (const float*)d_in[7];
    const float* W3   = (const float*)d_in[8];
    const float* b3   = (const float*)d_in[9];
    float* outp = (float*)d_out;

    u64t* halo = (u64t*)d_ws;                     // NBLK * 64 u64 (512 KB)

    // zero the whole mailbox each launch: tags embedded in data words must
    // not leak across graph replays (stale tag >= need hands out old rows)
    hipMemsetAsync(d_ws, 0, (size_t)NBLK * 64 * sizeof(u64t), stream);

    void* args[] = {(void*)&grid, (void*)&dtp, (void*)&W0, (void*)&b0,
                    (void*)&W1, (void*)&b1, (void*)&W2, (void*)&b2,
                    (void*)&W3, (void*)&b3, (void*)&outp, (void*)&halo};

    // Deterministic launch-mode choice (query enqueues nothing; capture-safe).
    // Coop launch caps grid at occupancy*256; need >=4 blocks/CU for 1024.
    // Fallback plain launch: all 1024 blocks fit simultaneously (8KB LDS,
    // 256 thr, VGPR bounded) -> spins stay live.
    int maxb = 0;
    hipError_t qe = hipOccupancyMaxActiveBlocksPerMultiprocessor(
        &maxb, (const void*)nfv_kernel, 256, 0);
    if (qe == hipSuccess && maxb >= 4) {
        hipLaunchCooperativeKernel((const void*)nfv_kernel,
                                   dim3(NBLK), dim3(256), args, 0, stream);
    } else {
        hipLaunchKernelGGL(nfv_kernel, dim3(NBLK), dim3(256), 0, stream,
                           grid, dtp, W0, b0, W1, b1, W2, b2, W3, b3,
                           outp, halo);
    }
}

// Round 15
// 188.389 us; speedup vs baseline: 1.4239x; 1.1710x over previous
//
#include <hip/hip_runtime.h>

#define NX 1024
#define NT 64
#define NBATCH 16
#define BPB 64           // blocks per batch chain (16 cells each)
#define NBLK (NBATCH * BPB)   // 1024 = 256 CUs x 4 blocks
#define DXC 0.02f
#define INV_SIG 20.0f
#define BIGF 1.0e6f

typedef __attribute__((ext_vector_type(8))) short bf16x8;
typedef __attribute__((ext_vector_type(4))) float f32x4;
typedef unsigned long long u64t;

// round-to-nearest-even f32 -> bf16
__device__ __forceinline__ unsigned short f2bf(float x) {
    unsigned u = __builtin_bit_cast(unsigned, x);
    u += 0x7FFFu + ((u >> 16) & 1u);
    return (unsigned short)(u >> 16);
}
__device__ __forceinline__ float bf2f(unsigned short h) {
    return __builtin_bit_cast(float, (unsigned)h << 16);
}
// HW packed f32x2 -> bf16x2 (lo = src0, hi = src1)
__device__ __forceinline__ unsigned cvt_pk_bf16(float lo, float hi) {
    unsigned r;
    asm("v_cvt_pk_bf16_f32 %0, %1, %2" : "=v"(r) : "v"(lo), "v"(hi));
    return r;
}
__device__ __forceinline__ float hw_exp2(float v) {
    float e;
    asm("v_exp_f32 %0, %1" : "=v"(e) : "v"(v));
    return e;
}

// tanh-form GELU, constants folded (|err vs exact erf-GELU| <= ~3e-4):
//   gelu(x) = x - x / (1 + exp2( x * (0.1029456*x^2 + 2.3022654) ))
//   where 2.3022654 = 2*log2(e)*sqrt(2/pi), 0.1029456 = that * 0.044715.
__device__ __forceinline__ float fast_gelu(float x) {
    float x2 = x * x;
    float v  = x * fmaf(0.1029456f, x2, 2.3022654f);
    float rc = __builtin_amdgcn_rcpf(hw_exp2(v) + 1.0f);
    return x - x * rc;
}

// SYSTEM-scope relaxed (L3 coherence point; no cache inv/wb) — cross-XCD safe.
__device__ __forceinline__ u64t sys_load_u64(const u64t* p) {
    return __hip_atomic_load(p, __ATOMIC_RELAXED, __HIP_MEMORY_SCOPE_SYSTEM);
}
__device__ __forceinline__ void sys_store_u64(u64t* p, u64t v) {
    __hip_atomic_store(p, v, __ATOMIC_RELAXED, __HIP_MEMORY_SCOPE_SYSTEM);
}

// XOR-swizzled [R][64] bf16 LDS layout: 16B chunk index XOR'd with row&7.
__device__ __forceinline__ int swz(int row, int k) {
    return (row << 6) + ((((k >> 3) ^ row) & 7) << 3) + (k & 7);
}

__global__ void __launch_bounds__(256, 4) nfv_kernel(
    const float* __restrict__ grid, const float* __restrict__ dtp,
    const float* __restrict__ W0, const float* __restrict__ b0,
    const float* __restrict__ W1, const float* __restrict__ b1,
    const float* __restrict__ W2, const float* __restrict__ b2,
    const float* __restrict__ W3, const float* __restrict__ b3,
    float* __restrict__ outp, u64t* __restrict__ halo)
{
    __shared__ float st_s[80];      // state strip, global [c0-32, c0+48)
    __shared__ __align__(16) unsigned short feat_s[16 * 64]; // bf16 features, swz
    __shared__ __align__(16) unsigned short actA[16 * 64];
    __shared__ __align__(16) unsigned short actB[16 * 64];
    __shared__ __align__(16) float part_s[16 * 20];          // [row][16 partials + pad]

    const int tid  = threadIdx.x;
    const int lane = tid & 63;
    const int wid  = tid >> 6;            // 0..3
    const int bid  = blockIdx.x;
    const int b    = bid >> 6;            // batch
    const int bb   = bid & 63;            // block within chain
    const int c0   = bb * 16;
    const float dtv = dtp[b];
    const float r   = dtv / DXC;
    const float b3v = b3[0];

    const float* grow = grid + (size_t)b * (NT * NX);
    float*       orow = outp + (size_t)b * (NT * NX);

    // fragment geometry: 4 waves = 1x4 tiles of 16x16 (M=16 cells, N=64 ch)
    const int l15 = lane & 15;
    const int kb0 = lane >> 4;                   // 16B-chunk idx: 0..3
    const int col = wid * 16 + l15;              // output channel (0..63)
    const int row0 = (lane >> 4) << 2;           // C rows: 0,4,8,12 (+j)
    const int arow = l15;                        // feat/act row (0..15)

    // ---- prologue: per-lane constant weight fragments (registers) ----
    // L0 refactor: W0[:,k]*s + W0[:,7+k]*(1-2s) = A_k*s + W0[:,7+k],
    //   A_k = W0[:,k]-2*W0[:,7+k]. Slot k: A_k (s_hi); slot 7+k: A_k (s_lo);
    //   slots 14..20: prox weights; 21: dt weight; 22..31: zero.
    bf16x8 w0f, w1fa, w1fb, w2fa, w2fb;
    {
        const int k0 = kb0 * 8;
        #pragma unroll
        for (int i = 0; i < 8; ++i) {
            int k = k0 + i;
            float wv;
            if (k < 7)       wv = W0[col * 22 + k] - 2.0f * W0[col * 22 + 7 + k];
            else if (k < 14) wv = W0[col * 22 + (k - 7)] - 2.0f * W0[col * 22 + k];
            else if (k < 22) wv = W0[col * 22 + k];
            else             wv = 0.0f;
            w0f[i]  = (short)f2bf(wv);
            w1fa[i] = (short)f2bf(W1[col * 64 + k0 + i]);
            w1fb[i] = (short)f2bf(W1[col * 64 + k0 + 32 + i]);
            w2fa[i] = (short)f2bf(W2[col * 64 + k0 + i]);
            w2fb[i] = (short)f2bf(W2[col * 64 + k0 + 32 + i]);
        }
    }
    float bias0 = b0[col];
    #pragma unroll
    for (int k = 7; k < 14; ++k) bias0 += W0[col * 22 + k];  // char constant fold
    const float bias1 = b1[col], bias2 = b2[col], w3c = W3[col];

    // ---- hoisted loop-invariant LDS addresses (named scalars, rule #20) ----
    const int aoffA = (arow << 6) + (((kb0    ) ^ arow) * 8 & 56);  // chunk kb0
    const int aoffB = (arow << 6) + ((((kb0+4) ^ arow) & 7) << 3);  // chunk kb0+4
    const bf16x8* const prF  = (const bf16x8*)(const void*)&feat_s[aoffA];
    const bf16x8* const prA0 = (const bf16x8*)(const void*)&actA[aoffA];
    const bf16x8* const prA1 = (const bf16x8*)(const void*)&actA[aoffB];
    const bf16x8* const prB0 = (const bf16x8*)(const void*)&actB[aoffA];
    const bf16x8* const prB1 = (const bf16x8*)(const void*)&actB[aoffB];
    unsigned short* const pwA0 = &actA[swz(row0    , col)];
    unsigned short* const pwA1 = &actA[swz(row0 + 1, col)];
    unsigned short* const pwA2 = &actA[swz(row0 + 2, col)];
    unsigned short* const pwA3 = &actA[swz(row0 + 3, col)];
    unsigned short* const pwB0 = &actB[swz(row0    , col)];
    unsigned short* const pwB1 = &actB[swz(row0 + 1, col)];
    unsigned short* const pwB2 = &actB[swz(row0 + 2, col)];
    unsigned short* const pwB3 = &actB[swz(row0 + 3, col)];
    const int poff = row0 * 20 + (wid << 2) + (l15 >> 2);   // part_s writer
    const bool pwrite = ((l15 & 3) == 0);

    // feature-phase constants
    const int fslot = wid * 2 + (lane >> 5);        // stencil slot 0..7
    const int frow  = lane & 15;
    const bool fact = (fslot < 7) && ((lane & 31) < 16);
    int fc = frow + 29 + fslot;                      // strip query cell
    if (bb == 0       && fc < 32) fc = 32;
    if (bb == BPB - 1 && fc > 47) fc = 47;
    const int foff0 = swz(frow, fslot);
    const int foff1 = swz(frow, 7 + fslot);
    const int foff2 = swz(frow, 14 + fslot);

    // halo-fill constants (wave0)
    int hg = (lane < 32) ? (c0 - 32 + lane) : (c0 - 16 + lane);
    hg = hg < 0 ? 0 : (hg > NX - 1 ? NX - 1 : hg);
    const u64t* const hbase = &halo[(size_t)(b * BPB + (hg >> 4)) * 64 + (hg & 15)];
    const int hdst = (lane < 32) ? lane : lane + 16;

    // update-phase constants (wave0, lanes 0..15)
    const f32x4* const pru = (const f32x4*)(const void*)&part_s[l15 * 20];
    u64t* const hpub = &halo[(size_t)bid * 64 + l15];
    float* const ocell = orow + c0 + l15;

    ((unsigned*)feat_s)[tid]       = 0;    // zero all 1024 bf16 entries
    ((unsigned*)feat_s)[tid + 256] = 0;    // (pad K slots stay 0 forever)
    if (tid < 16) {
        orow[c0 + tid] = grow[c0 + tid];   // t = 0 output
        feat_s[swz(tid, 21)] = f2bf(dtv);  // dt slot: constant, write once
    }
    if (tid < 80) {                        // initial strip (row 0), edge-clamped
        int ga = c0 - 32 + tid;
        ga = ga < 0 ? 0 : (ga > NX - 1 ? NX - 1 : ga);
        st_s[tid] = grow[ga];
    }

    for (int t = 1; t < NT; ++t) {
        // ---- wave0: fill 64 halo cells for row t-1 (fused data+tag/lane) ----
        if (wid == 0 && t >= 2) {
            const unsigned need = (unsigned)(t - 1);
            const u64t* src = hbase + (size_t)(((t - 1) & 3) * 16);
            u64t u;
            do { u = sys_load_u64(src); } while ((unsigned)(u >> 32) < need);
            st_s[hdst] = __builtin_bit_cast(float, (unsigned)u);
        }
        __syncthreads();   // A: strip (row t-1) complete (covers prologue @t=1)

        // ---- all waves: ballot prox + features ----
        {
            // shock ballots over strip pairs p=0..78 (pair p: cells p,p+1)
            bool q0 = st_s[lane + 1] > st_s[lane];               // pairs 0..63
            bool q1 = (lane < 15) && (st_s[65 + lane] > st_s[64 + lane]);
            u64t m0 = __ballot(q0);
            u64t m1 = __ballot(q1);
            if (fact) {
                const int c = fc;
                float dL = BIGF, dR = BIGF;
                u64t sello = m0 & (((u64t)1 << c) - 1); // pairs <= c-1
                if (sello) dL = (float)(c - (63 - __builtin_clzll(sello))) - 0.5f;
                u64t r0 = m0 >> c;                      // pairs >= c
                if (r0)      dR = (float)__builtin_ctzll(r0) + 0.5f;
                else if (m1) dR = (float)(64 - c + __builtin_ctzll(m1)) + 0.5f;
                float d = fminf(dL, dR);                // in cell units
                float prox = hw_exp2(d * -0.5770780f);  // exp(-0.4 d)

                float sv = st_s[c];
                unsigned short shi = f2bf(sv);
                unsigned short slo = f2bf(sv - bf2f(shi));  // double-bf16 state
                feat_s[foff0] = shi;
                feat_s[foff1] = slo;
                feat_s[foff2] = f2bf(prox);
            }
        }
        __syncthreads();   // B: features ready

        // ---- L0 (1x MFMA bf16, K=32): feat x W0'^T -> actA ----
        {
            f32x4 c4 = {0.0f, 0.0f, 0.0f, 0.0f};
            c4 = __builtin_amdgcn_mfma_f32_16x16x32_bf16(*prF, w0f, c4, 0, 0, 0);
            unsigned u01 = cvt_pk_bf16(fast_gelu(c4[0] + bias0), fast_gelu(c4[1] + bias0));
            unsigned u23 = cvt_pk_bf16(fast_gelu(c4[2] + bias0), fast_gelu(c4[3] + bias0));
            *pwA0 = (unsigned short)u01;
            *pwA1 = (unsigned short)(u01 >> 16);
            *pwA2 = (unsigned short)u23;
            *pwA3 = (unsigned short)(u23 >> 16);
        }
        __syncthreads();   // C: actA ready

        // ---- L1 (MFMA bf16, K=64): actA x W1^T -> actB ----
        {
            f32x4 c4 = {0.0f, 0.0f, 0.0f, 0.0f};
            c4 = __builtin_amdgcn_mfma_f32_16x16x32_bf16(*prA0, w1fa, c4, 0, 0, 0);
            c4 = __builtin_amdgcn_mfma_f32_16x16x32_bf16(*prA1, w1fb, c4, 0, 0, 0);
            unsigned u01 = cvt_pk_bf16(fast_gelu(c4[0] + bias1), fast_gelu(c4[1] + bias1));
            unsigned u23 = cvt_pk_bf16(fast_gelu(c4[2] + bias1), fast_gelu(c4[3] + bias1));
            *pwB0 = (unsigned short)u01;
            *pwB1 = (unsigned short)(u01 >> 16);
            *pwB2 = (unsigned short)u23;
            *pwB3 = (unsigned short)(u23 >> 16);
        }
        __syncthreads();   // D: actB ready

        // ---- L2 (MFMA bf16) + fused L3 partial (2-stage shfl -> 16/row) ----
        {
            f32x4 c4 = {0.0f, 0.0f, 0.0f, 0.0f};
            c4 = __builtin_amdgcn_mfma_f32_16x16x32_bf16(*prB0, w2fa, c4, 0, 0, 0);
            c4 = __builtin_amdgcn_mfma_f32_16x16x32_bf16(*prB1, w2fb, c4, 0, 0, 0);
            #pragma unroll
            for (int j = 0; j < 4; ++j) {
                float p = w3c * fast_gelu(c4[j] + bias2);
                p += __shfl_xor(p, 1);
                p += __shfl_xor(p, 2);
                if (pwrite) part_s[poff + j * 20] = p;
            }
        }
        __syncthreads();   // E: partials ready

        // ---- wave0: update + publish + store ----
        if (wid == 0 && lane < 16) {
            f32x4 s4 = pru[0] + pru[1] + pru[2] + pru[3];
            float sum = s4[0] + s4[1] + s4[2] + s4[3];
            float ns = st_s[32 + l15] + r * (sum + b3v);
            ns = fminf(1.0f, fmaxf(0.0f, ns));
            if (t < NT - 1) {
                u64t u = ((u64t)(unsigned)t << 32) |
                         (u64t)(unsigned)__builtin_bit_cast(unsigned, ns);
                sys_store_u64(hpub + (size_t)((t & 3) * 16), u);
            }
            ocell[(size_t)t * NX] = ns;
            st_s[32 + l15] = ns;
        }
        // next iter's barrier A guards st_s/feat_s/actA/part_s reuse
    }
}

extern "C" void kernel_launch(void* const* d_in, const int* in_sizes, int n_in,
                              void* d_out, int out_size, void* d_ws, size_t ws_size,
                              hipStream_t stream) {
    const float* grid = (const float*)d_in[0];
    const float* dtp  = (const float*)d_in[1];
    const float* W0   = (const float*)d_in[2];
    const float* b0   = (const float*)d_in[3];
    const float* W1   = (const float*)d_in[4];
    const float* b1   = (const float*)d_in[5];
    const float* W2   = (const float*)d_in[6];
    const float* b2   = (const float*)d_in[7];
    const float* W3   = (const float*)d_in[8];
    const float* b3   = (const float*)d_in[9];
    float* outp = (float*)d_out;

    u64t* halo = (u64t*)d_ws;                     // NBLK * 64 u64 (512 KB)

    // zero the whole mailbox each launch: tags embedded in data words must
    // not leak across graph replays (stale tag >= need hands out old rows)
    hipMemsetAsync(d_ws, 0, (size_t)NBLK * 64 * sizeof(u64t), stream);

    void* args[] = {(void*)&grid, (void*)&dtp, (void*)&W0, (void*)&b0,
                    (void*)&W1, (void*)&b1, (void*)&W2, (void*)&b2,
                    (void*)&W3, (void*)&b3, (void*)&outp, (void*)&halo};

    // Deterministic launch-mode choice (query enqueues nothing; capture-safe).
    // Coop launch caps grid at occupancy*256; need >=4 blocks/CU for 1024.
    // Fallback plain launch: all 1024 blocks fit simultaneously (8KB LDS,
    // 256 thr, VGPR bounded) -> spins stay live.
    int maxb = 0;
    hipError_t qe = hipOccupancyMaxActiveBlocksPerMultiprocessor(
        &maxb, (const void*)nfv_kernel, 256, 0);
    if (qe == hipSuccess && maxb >= 4) {
        hipLaunchCooperativeKernel((const void*)nfv_kernel,
                                   dim3(NBLK), dim3(256), args, 0, stream);
    } else {
        hipLaunchKernelGGL(nfv_kernel, dim3(NBLK), dim3(256), 0, stream,
                           grid, dtp, W0, b0, W1, b1, W2, b2, W3, b3,
                           outp, halo);
    }
}

// Round 16
// 186.124 us; speedup vs baseline: 1.4412x; 1.0122x over previous
//
#include <hip/hip_runtime.h>

#define NX 1024
#define NT 64
#define NBATCH 16
#define BPB 64           // blocks per batch chain (16 cells each)
#define NBLK (NBATCH * BPB)   // 1024 = 256 CUs x 4 blocks
#define DXC 0.02f
#define INV_SIG 20.0f
#define BIGF 1.0e6f

typedef __attribute__((ext_vector_type(8))) short bf16x8;
typedef __attribute__((ext_vector_type(4))) float f32x4;
typedef unsigned long long u64t;

// round-to-nearest-even f32 -> bf16
__device__ __forceinline__ unsigned short f2bf(float x) {
    unsigned u = __builtin_bit_cast(unsigned, x);
    u += 0x7FFFu + ((u >> 16) & 1u);
    return (unsigned short)(u >> 16);
}
__device__ __forceinline__ float bf2f(unsigned short h) {
    return __builtin_bit_cast(float, (unsigned)h << 16);
}
// HW packed f32x2 -> bf16x2 (lo = src0, hi = src1)
__device__ __forceinline__ unsigned cvt_pk_bf16(float lo, float hi) {
    unsigned r;
    asm("v_cvt_pk_bf16_f32 %0, %1, %2" : "=v"(r) : "v"(lo), "v"(hi));
    return r;
}
__device__ __forceinline__ float hw_exp2(float v) {
    float e;
    asm("v_exp_f32 %0, %1" : "=v"(e) : "v"(v));
    return e;
}

// tanh-form GELU, constants folded (|err vs exact erf-GELU| <= ~3e-4):
//   gelu(x) = x - x / (1 + exp2( x * (0.1029456*x^2 + 2.3022654) ))
__device__ __forceinline__ float fast_gelu(float x) {
    float x2 = x * x;
    float v  = x * fmaf(0.1029456f, x2, 2.3022654f);
    float rc = __builtin_amdgcn_rcpf(hw_exp2(v) + 1.0f);
    return x - x * rc;
}

// SYSTEM-scope relaxed (L3 coherence point; no cache inv/wb) — cross-XCD safe.
__device__ __forceinline__ u64t sys_load_u64(const u64t* p) {
    return __hip_atomic_load(p, __ATOMIC_RELAXED, __HIP_MEMORY_SCOPE_SYSTEM);
}
__device__ __forceinline__ void sys_store_u64(u64t* p, u64t v) {
    __hip_atomic_store(p, v, __ATOMIC_RELAXED, __HIP_MEMORY_SCOPE_SYSTEM);
}

// XOR-swizzled [R][64] bf16 LDS layout: 16B chunk index XOR'd with row&7.
__device__ __forceinline__ int swz(int row, int k) {
    return (row << 6) + ((((k >> 3) ^ row) & 7) << 3) + (k & 7);
}

__global__ void __launch_bounds__(256, 4) nfv_kernel(
    const float* __restrict__ grid, const float* __restrict__ dtp,
    const float* __restrict__ W0, const float* __restrict__ b0,
    const float* __restrict__ W1, const float* __restrict__ b1,
    const float* __restrict__ W2, const float* __restrict__ b2,
    const float* __restrict__ W3, const float* __restrict__ b3,
    float* __restrict__ outp, u64t* __restrict__ halo)
{
    __shared__ float st_s[80];      // state strip, global [c0-32, c0+48)
    __shared__ __align__(16) unsigned short feat_s[16 * 64]; // bf16 features, swz
    __shared__ __align__(16) unsigned short actA[16 * 64];
    __shared__ __align__(16) unsigned short actB[16 * 64];
    __shared__ __align__(16) float part_s[16 * 20];          // [row][16 partials + pad]

    const int tid  = threadIdx.x;
    const int lane = tid & 63;
    const int wid  = tid >> 6;            // 0..3
    const int bid  = blockIdx.x;
    const int b    = bid >> 6;            // batch
    const int bb   = bid & 63;            // block within chain
    const int c0   = bb * 16;
    const float dtv = dtp[b];
    const float r   = dtv / DXC;
    const float b3v = b3[0];

    const float* grow = grid + (size_t)b * (NT * NX);
    float*       orow = outp + (size_t)b * (NT * NX);

    // fragment geometry: 4 waves = 1x4 tiles of 16x16 (M=16 cells, N=64 ch)
    const int l15 = lane & 15;
    const int kb0 = lane >> 4;                   // 16B-chunk idx: 0..3
    const int col = wid * 16 + l15;              // output channel (0..63)
    const int row0 = (lane >> 4) << 2;           // C rows: 0,4,8,12 (+j)
    const int arow = l15;                        // feat/act row (0..15)

    // ---- prologue: per-lane constant weight fragments (registers) ----
    // L0 refactor: W0[:,k]*s + W0[:,7+k]*(1-2s) = A_k*s + W0[:,7+k],
    //   A_k = W0[:,k]-2*W0[:,7+k]. Slot k: A_k (s_hi); slot 7+k: A_k (s_lo);
    //   slots 14..20: prox weights; 21: dt weight; 22..31: zero.
    bf16x8 w0f, w1fa, w1fb, w2fa, w2fb;
    {
        const int k0 = kb0 * 8;
        #pragma unroll
        for (int i = 0; i < 8; ++i) {
            int k = k0 + i;
            float wv;
            if (k < 7)       wv = W0[col * 22 + k] - 2.0f * W0[col * 22 + 7 + k];
            else if (k < 14) wv = W0[col * 22 + (k - 7)] - 2.0f * W0[col * 22 + k];
            else if (k < 22) wv = W0[col * 22 + k];
            else             wv = 0.0f;
            w0f[i]  = (short)f2bf(wv);
            w1fa[i] = (short)f2bf(W1[col * 64 + k0 + i]);
            w1fb[i] = (short)f2bf(W1[col * 64 + k0 + 32 + i]);
            w2fa[i] = (short)f2bf(W2[col * 64 + k0 + i]);
            w2fb[i] = (short)f2bf(W2[col * 64 + k0 + 32 + i]);
        }
    }
    float bias0 = b0[col];
    #pragma unroll
    for (int k = 7; k < 14; ++k) bias0 += W0[col * 22 + k];  // char constant fold
    const float bias1 = b1[col], bias2 = b2[col], w3c = W3[col];

    // ---- hoisted loop-invariant LDS addresses (named scalars, rule #20) ----
    const int aoffA = (arow << 6) + (((kb0    ) ^ arow) * 8 & 56);  // chunk kb0
    const int aoffB = (arow << 6) + ((((kb0+4) ^ arow) & 7) << 3);  // chunk kb0+4
    const bf16x8* const prF  = (const bf16x8*)(const void*)&feat_s[aoffA];
    const bf16x8* const prA0 = (const bf16x8*)(const void*)&actA[aoffA];
    const bf16x8* const prA1 = (const bf16x8*)(const void*)&actA[aoffB];
    const bf16x8* const prB0 = (const bf16x8*)(const void*)&actB[aoffA];
    const bf16x8* const prB1 = (const bf16x8*)(const void*)&actB[aoffB];
    unsigned short* const pwA0 = &actA[swz(row0    , col)];
    unsigned short* const pwA1 = &actA[swz(row0 + 1, col)];
    unsigned short* const pwA2 = &actA[swz(row0 + 2, col)];
    unsigned short* const pwA3 = &actA[swz(row0 + 3, col)];
    unsigned short* const pwB0 = &actB[swz(row0    , col)];
    unsigned short* const pwB1 = &actB[swz(row0 + 1, col)];
    unsigned short* const pwB2 = &actB[swz(row0 + 2, col)];
    unsigned short* const pwB3 = &actB[swz(row0 + 3, col)];
    const int poff = row0 * 20 + (wid << 2) + (l15 >> 2);   // part_s writer
    const bool pwrite = ((l15 & 3) == 0);

    // feature-phase constants
    const int fslot = wid * 2 + (lane >> 5);        // stencil slot 0..7
    const int frow  = lane & 15;
    const bool fact = (fslot < 7) && ((lane & 31) < 16);
    int fc = frow + 29 + fslot;                      // strip query cell
    if (bb == 0       && fc < 32) fc = 32;
    if (bb == BPB - 1 && fc > 47) fc = 47;
    const int foff0 = swz(frow, fslot);
    const int foff1 = swz(frow, 7 + fslot);
    const int foff2 = swz(frow, 14 + fslot);

    // halo-poll constants (wave1 in E-window)
    int hg = (lane < 32) ? (c0 - 32 + lane) : (c0 - 16 + lane);
    hg = hg < 0 ? 0 : (hg > NX - 1 ? NX - 1 : hg);
    const u64t* const hbase = &halo[(size_t)(b * BPB + (hg >> 4)) * 64 + (hg & 15)];
    const int hdst = (lane < 32) ? lane : lane + 16;

    // update-phase constants (wave0, lanes 0..15)
    const f32x4* const pru = (const f32x4*)(const void*)&part_s[l15 * 20];
    u64t* const hpub = &halo[(size_t)bid * 64 + l15];
    float* const ocell = orow + c0 + l15;

    ((unsigned*)feat_s)[tid]       = 0;    // zero all 1024 bf16 entries
    ((unsigned*)feat_s)[tid + 256] = 0;    // (pad K slots stay 0 forever)
    if (tid < 16) {
        orow[c0 + tid] = grow[c0 + tid];   // t = 0 output
        feat_s[swz(tid, 21)] = f2bf(dtv);  // dt slot: constant, write once
    }
    if (tid < 80) {                        // initial strip (row 0), edge-clamped
        int ga = c0 - 32 + tid;
        ga = ga < 0 ? 0 : (ga > NX - 1 ? NX - 1 : ga);
        st_s[tid] = grow[ga];
    }
    __syncthreads();   // prologue complete; strip holds row 0

    for (int t = 1; t < NT; ++t) {
        // ---- all waves: ballot prox + features (st_s = row t-1) ----
        {
            // shock ballots over strip pairs p=0..78 (pair p: cells p,p+1)
            bool q0 = st_s[lane + 1] > st_s[lane];               // pairs 0..63
            bool q1 = (lane < 15) && (st_s[65 + lane] > st_s[64 + lane]);
            u64t m0 = __ballot(q0);
            u64t m1 = __ballot(q1);
            if (fact) {
                const int c = fc;
                float dL = BIGF, dR = BIGF;
                u64t sello = m0 & (((u64t)1 << c) - 1); // pairs <= c-1
                if (sello) dL = (float)(c - (63 - __builtin_clzll(sello))) - 0.5f;
                u64t r0 = m0 >> c;                      // pairs >= c
                if (r0)      dR = (float)__builtin_ctzll(r0) + 0.5f;
                else if (m1) dR = (float)(64 - c + __builtin_ctzll(m1)) + 0.5f;
                float d = fminf(dL, dR);                // in cell units
                float prox = hw_exp2(d * -0.5770780f);  // exp(-0.4 d)

                float sv = st_s[c];
                unsigned short shi = f2bf(sv);
                unsigned short slo = f2bf(sv - bf2f(shi));  // double-bf16 state
                feat_s[foff0] = shi;
                feat_s[foff1] = slo;
                feat_s[foff2] = f2bf(prox);
            }
        }
        __syncthreads();   // B: features ready

        // ---- L0 (1x MFMA bf16, K=32): feat x W0'^T -> actA ----
        {
            f32x4 c4 = {0.0f, 0.0f, 0.0f, 0.0f};
            c4 = __builtin_amdgcn_mfma_f32_16x16x32_bf16(*prF, w0f, c4, 0, 0, 0);
            unsigned u01 = cvt_pk_bf16(fast_gelu(c4[0] + bias0), fast_gelu(c4[1] + bias0));
            unsigned u23 = cvt_pk_bf16(fast_gelu(c4[2] + bias0), fast_gelu(c4[3] + bias0));
            *pwA0 = (unsigned short)u01;
            *pwA1 = (unsigned short)(u01 >> 16);
            *pwA2 = (unsigned short)u23;
            *pwA3 = (unsigned short)(u23 >> 16);
        }
        __syncthreads();   // C: actA ready

        // ---- L1 (MFMA bf16, K=64): actA x W1^T -> actB ----
        {
            f32x4 c4 = {0.0f, 0.0f, 0.0f, 0.0f};
            c4 = __builtin_amdgcn_mfma_f32_16x16x32_bf16(*prA0, w1fa, c4, 0, 0, 0);
            c4 = __builtin_amdgcn_mfma_f32_16x16x32_bf16(*prA1, w1fb, c4, 0, 0, 0);
            unsigned u01 = cvt_pk_bf16(fast_gelu(c4[0] + bias1), fast_gelu(c4[1] + bias1));
            unsigned u23 = cvt_pk_bf16(fast_gelu(c4[2] + bias1), fast_gelu(c4[3] + bias1));
            *pwB0 = (unsigned short)u01;
            *pwB1 = (unsigned short)(u01 >> 16);
            *pwB2 = (unsigned short)u23;
            *pwB3 = (unsigned short)(u23 >> 16);
        }
        __syncthreads();   // D: actB ready

        // ---- L2 (MFMA bf16) + fused L3 partial (2-stage shfl -> 16/row) ----
        {
            f32x4 c4 = {0.0f, 0.0f, 0.0f, 0.0f};
            c4 = __builtin_amdgcn_mfma_f32_16x16x32_bf16(*prB0, w2fa, c4, 0, 0, 0);
            c4 = __builtin_amdgcn_mfma_f32_16x16x32_bf16(*prB1, w2fb, c4, 0, 0, 0);
            #pragma unroll
            for (int j = 0; j < 4; ++j) {
                float p = w3c * fast_gelu(c4[j] + bias2);
                p += __shfl_xor(p, 1);
                p += __shfl_xor(p, 2);
                if (pwrite) part_s[poff + j * 20] = p;
            }
        }
        __syncthreads();   // E: partials ready

        // ---- E->A window: wave0 update+publish  ||  wave1 poll row t halo ----
        // Disjoint st_s regions: wave0 writes [32..47]; wave1 writes [0..31],
        // [64..79]. Edge blocks' clamped lanes self-poll the word wave0 is
        // publishing in this same window — wave0 never waits on wave1 (live).
        if (wid == 0 && lane < 16) {
            f32x4 s4 = pru[0] + pru[1] + pru[2] + pru[3];
            float sum = s4[0] + s4[1] + s4[2] + s4[3];
            float ns = st_s[32 + l15] + r * (sum + b3v);
            ns = fminf(1.0f, fmaxf(0.0f, ns));
            if (t < NT - 1) {
                u64t u = ((u64t)(unsigned)t << 32) |
                         (u64t)(unsigned)__builtin_bit_cast(unsigned, ns);
                sys_store_u64(hpub + (size_t)((t & 3) * 16), u);
            }
            ocell[(size_t)t * NX] = ns;
            st_s[32 + l15] = ns;
        } else if (wid == 1 && t < NT - 1) {
            // fill strip halo with row t from neighbors (fused data+tag/lane);
            // consumed by next iteration's feature phase after barrier A
            const unsigned need = (unsigned)t;
            const u64t* src = hbase + (size_t)((t & 3) * 16);
            u64t u;
            do { u = sys_load_u64(src); } while ((unsigned)(u >> 32) < need);
            st_s[hdst] = __builtin_bit_cast(float, (unsigned)u);
        }
        __syncthreads();   // A: strip now holds row t (+ halo); next iteration
    }
}

extern "C" void kernel_launch(void* const* d_in, const int* in_sizes, int n_in,
                              void* d_out, int out_size, void* d_ws, size_t ws_size,
                              hipStream_t stream) {
    const float* grid = (const float*)d_in[0];
    const float* dtp  = (const float*)d_in[1];
    const float* W0   = (const float*)d_in[2];
    const float* b0   = (const float*)d_in[3];
    const float* W1   = (const float*)d_in[4];
    const float* b1   = (const float*)d_in[5];
    const float* W2   = (const float*)d_in[6];
    const float* b2   = (const float*)d_in[7];
    const float* W3   = (const float*)d_in[8];
    const float* b3   = (const float*)d_in[9];
    float* outp = (float*)d_out;

    u64t* halo = (u64t*)d_ws;                     // NBLK * 64 u64 (512 KB)

    // zero the whole mailbox each launch: tags embedded in data words must
    // not leak across graph replays (stale tag >= need hands out old rows)
    hipMemsetAsync(d_ws, 0, (size_t)NBLK * 64 * sizeof(u64t), stream);

    void* args[] = {(void*)&grid, (void*)&dtp, (void*)&W0, (void*)&b0,
                    (void*)&W1, (void*)&b1, (void*)&W2, (void*)&b2,
                    (void*)&W3, (void*)&b3, (void*)&outp, (void*)&halo};

    // Deterministic launch-mode choice (query enqueues nothing; capture-safe).
    // Coop launch caps grid at occupancy*256; need >=4 blocks/CU for 1024.
    // Fallback plain launch: all 1024 blocks fit simultaneously (8KB LDS,
    // 256 thr, VGPR bounded) -> spins stay live.
    int maxb = 0;
    hipError_t qe = hipOccupancyMaxActiveBlocksPerMultiprocessor(
        &maxb, (const void*)nfv_kernel, 256, 0);
    if (qe == hipSuccess && maxb >= 4) {
        hipLaunchCooperativeKernel((const void*)nfv_kernel,
                                   dim3(NBLK), dim3(256), args, 0, stream);
    } else {
        hipLaunchKernelGGL(nfv_kernel, dim3(NBLK), dim3(256), 0, stream,
                           grid, dtp, W0, b0, W1, b1, W2, b2, W3, b3,
                           outp, halo);
    }
}

// Round 18
// 183.280 us; speedup vs baseline: 1.4635x; 1.0155x over previous
//
#include <hip/hip_runtime.h>

#define NX 1024
#define NT 64
#define NBATCH 16
#define BPB 64           // blocks per batch chain (16 cells each)
#define NBLK (NBATCH * BPB)   // 1024 = 256 CUs x 4 blocks
#define DXC 0.02f
#define INV_SIG 20.0f
#define BIGF 1.0e6f

typedef __attribute__((ext_vector_type(8))) short bf16x8;
typedef __attribute__((ext_vector_type(4))) float f32x4;
typedef __attribute__((ext_vector_type(2))) float f32x2;
typedef unsigned long long u64t;

// round-to-nearest-even f32 -> bf16
__device__ __forceinline__ unsigned short f2bf(float x) {
    unsigned u = __builtin_bit_cast(unsigned, x);
    u += 0x7FFFu + ((u >> 16) & 1u);
    return (unsigned short)(u >> 16);
}
__device__ __forceinline__ float bf2f(unsigned short h) {
    return __builtin_bit_cast(float, (unsigned)h << 16);
}
// HW packed f32x2 -> bf16x2 (lo = src0, hi = src1) — proven r9-r16
__device__ __forceinline__ unsigned cvt_pk_bf16(float lo, float hi) {
    unsigned r;
    asm("v_cvt_pk_bf16_f32 %0, %1, %2" : "=v"(r) : "v"(lo), "v"(hi));
    return r;
}
__device__ __forceinline__ float hw_exp2(float v) {
    float e;
    asm("v_exp_f32 %0, %1" : "=v"(e) : "v"(v));
    return e;
}

// 2-wide tanh-form GELU in native vector C (no VOP3P asm — r17 lesson:
// hand-written v_pk_* asm has op_sel_hi default pitfalls; let LLVM pack).
//   gelu(x) = x - x / (1 + exp2( x * (0.1029456*x^2 + 2.3022654) ))
__device__ __forceinline__ f32x2 pk_gelu(f32x2 x) {
    f32x2 x2 = x * x;
    f32x2 v  = x * (x2 * 0.1029456f + 2.3022654f);
    f32x2 rc;
    rc.x = __builtin_amdgcn_rcpf(hw_exp2(v.x) + 1.0f);
    rc.y = __builtin_amdgcn_rcpf(hw_exp2(v.y) + 1.0f);
    return x - x * rc;
}

// SYSTEM-scope relaxed (L3 coherence point; no cache inv/wb) — cross-XCD safe.
__device__ __forceinline__ u64t sys_load_u64(const u64t* p) {
    return __hip_atomic_load(p, __ATOMIC_RELAXED, __HIP_MEMORY_SCOPE_SYSTEM);
}
__device__ __forceinline__ void sys_store_u64(u64t* p, u64t v) {
    __hip_atomic_store(p, v, __ATOMIC_RELAXED, __HIP_MEMORY_SCOPE_SYSTEM);
}

// XOR-swizzled [R][64] bf16 LDS layout: 16B chunk index XOR'd with row&7.
__device__ __forceinline__ int swz(int row, int k) {
    return (row << 6) + ((((k >> 3) ^ row) & 7) << 3) + (k & 7);
}

__global__ void __launch_bounds__(256, 4) nfv_kernel(
    const float* __restrict__ grid, const float* __restrict__ dtp,
    const float* __restrict__ W0, const float* __restrict__ b0,
    const float* __restrict__ W1, const float* __restrict__ b1,
    const float* __restrict__ W2, const float* __restrict__ b2,
    const float* __restrict__ W3, const float* __restrict__ b3,
    float* __restrict__ outp, u64t* __restrict__ halo)
{
    __shared__ float st_s[80];      // state strip, global [c0-32, c0+48)
    __shared__ __align__(16) unsigned short feat_s[16 * 64]; // bf16 features, swz
    __shared__ __align__(16) unsigned short actA[16 * 64];
    __shared__ __align__(16) unsigned short actB[16 * 64];
    __shared__ __align__(16) float part_s[16 * 20];          // [row][16 partials + pad]

    const int tid  = threadIdx.x;
    const int lane = tid & 63;
    const int wid  = tid >> 6;            // 0..3
    const int bid  = blockIdx.x;
    const int b    = bid >> 6;            // batch
    const int bb   = bid & 63;            // block within chain
    const int c0   = bb * 16;
    const float dtv = dtp[b];
    const float r   = dtv / DXC;
    const float b3v = b3[0];

    const float* grow = grid + (size_t)b * (NT * NX);
    float*       orow = outp + (size_t)b * (NT * NX);

    // fragment geometry: 4 waves = 1x4 tiles of 16x16 (M=16 cells, N=64 ch)
    const int l15 = lane & 15;
    const int kb0 = lane >> 4;                   // 16B-chunk idx: 0..3
    const int col = wid * 16 + l15;              // output channel (0..63)
    const int row0 = (lane >> 4) << 2;           // C rows: 0,4,8,12 (+j)
    const int arow = l15;                        // feat/act row (0..15)

    // ---- prologue: per-lane constant weight fragments (registers) ----
    // L0 refactor: W0[:,k]*s + W0[:,7+k]*(1-2s) = A_k*s + W0[:,7+k],
    //   A_k = W0[:,k]-2*W0[:,7+k]. Slot k: A_k (s_hi); slot 7+k: A_k (s_lo);
    //   slots 14..20: prox weights; 21: dt weight; 22..31: zero.
    bf16x8 w0f, w1fa, w1fb, w2fa, w2fb;
    {
        const int k0 = kb0 * 8;
        #pragma unroll
        for (int i = 0; i < 8; ++i) {
            int k = k0 + i;
            float wv;
            if (k < 7)       wv = W0[col * 22 + k] - 2.0f * W0[col * 22 + 7 + k];
            else if (k < 14) wv = W0[col * 22 + (k - 7)] - 2.0f * W0[col * 22 + k];
            else if (k < 22) wv = W0[col * 22 + k];
            else             wv = 0.0f;
            w0f[i]  = (short)f2bf(wv);
            w1fa[i] = (short)f2bf(W1[col * 64 + k0 + i]);
            w1fb[i] = (short)f2bf(W1[col * 64 + k0 + 32 + i]);
            w2fa[i] = (short)f2bf(W2[col * 64 + k0 + i]);
            w2fb[i] = (short)f2bf(W2[col * 64 + k0 + 32 + i]);
        }
    }
    float bias0 = b0[col];
    #pragma unroll
    for (int k = 7; k < 14; ++k) bias0 += W0[col * 22 + k];  // char constant fold
    const float bias1 = b1[col], bias2 = b2[col], w3c = W3[col];

    // ---- hoisted loop-invariant LDS addresses (named scalars, rule #20) ----
    const int aoffA = (arow << 6) + (((kb0    ) ^ arow) * 8 & 56);  // chunk kb0
    const int aoffB = (arow << 6) + ((((kb0+4) ^ arow) & 7) << 3);  // chunk kb0+4
    const bf16x8* const prF  = (const bf16x8*)(const void*)&feat_s[aoffA];
    const bf16x8* const prA0 = (const bf16x8*)(const void*)&actA[aoffA];
    const bf16x8* const prA1 = (const bf16x8*)(const void*)&actA[aoffB];
    const bf16x8* const prB0 = (const bf16x8*)(const void*)&actB[aoffA];
    const bf16x8* const prB1 = (const bf16x8*)(const void*)&actB[aoffB];
    unsigned short* const pwA0 = &actA[swz(row0    , col)];
    unsigned short* const pwA1 = &actA[swz(row0 + 1, col)];
    unsigned short* const pwA2 = &actA[swz(row0 + 2, col)];
    unsigned short* const pwA3 = &actA[swz(row0 + 3, col)];
    unsigned short* const pwB0 = &actB[swz(row0    , col)];
    unsigned short* const pwB1 = &actB[swz(row0 + 1, col)];
    unsigned short* const pwB2 = &actB[swz(row0 + 2, col)];
    unsigned short* const pwB3 = &actB[swz(row0 + 3, col)];
    const int poff = row0 * 20 + (wid << 2) + (l15 >> 2);   // part_s writer
    const bool pwrite = ((l15 & 3) == 0);

    // feature-phase constants
    const int fslot = wid * 2 + (lane >> 5);        // stencil slot 0..7
    const int frow  = lane & 15;
    const bool fact = (fslot < 7) && ((lane & 31) < 16);
    int fc = frow + 29 + fslot;                      // strip query cell
    if (bb == 0       && fc < 32) fc = 32;
    if (bb == BPB - 1 && fc > 47) fc = 47;
    const int foff0 = swz(frow, fslot);
    const int foff1 = swz(frow, 7 + fslot);
    const int foff2 = swz(frow, 14 + fslot);

    // halo-poll constants (wave1 in E-window)
    int hg = (lane < 32) ? (c0 - 32 + lane) : (c0 - 16 + lane);
    hg = hg < 0 ? 0 : (hg > NX - 1 ? NX - 1 : hg);
    const u64t* const hbase = &halo[(size_t)(b * BPB + (hg >> 4)) * 64 + (hg & 15)];
    const int hdst = (lane < 32) ? lane : lane + 16;

    // update-phase constants (wave0, lanes 0..15)
    const f32x4* const pru = (const f32x4*)(const void*)&part_s[l15 * 20];
    u64t* const hpub = &halo[(size_t)bid * 64 + l15];
    float* const ocell = orow + c0 + l15;

    ((unsigned*)feat_s)[tid]       = 0;    // zero all 1024 bf16 entries
    ((unsigned*)feat_s)[tid + 256] = 0;    // (pad K slots stay 0 forever)
    if (tid < 16) {
        orow[c0 + tid] = grow[c0 + tid];   // t = 0 output
        feat_s[swz(tid, 21)] = f2bf(dtv);  // dt slot: constant, write once
    }
    if (tid < 80) {                        // initial strip (row 0), edge-clamped
        int ga = c0 - 32 + tid;
        ga = ga < 0 ? 0 : (ga > NX - 1 ? NX - 1 : ga);
        st_s[tid] = grow[ga];
    }
    __syncthreads();   // prologue complete; strip holds row 0

    for (int t = 1; t < NT; ++t) {
        // ---- all waves: ballot prox + features (st_s = row t-1) ----
        {
            // shock ballots over strip pairs p=0..78 (pair p: cells p,p+1)
            bool q0 = st_s[lane + 1] > st_s[lane];               // pairs 0..63
            bool q1 = (lane < 15) && (st_s[65 + lane] > st_s[64 + lane]);
            u64t m0 = __ballot(q0);
            u64t m1 = __ballot(q1);
            if (fact) {
                const int c = fc;
                float dL = BIGF, dR = BIGF;
                u64t sello = m0 & (((u64t)1 << c) - 1); // pairs <= c-1
                if (sello) dL = (float)(c - (63 - __builtin_clzll(sello))) - 0.5f;
                u64t r0 = m0 >> c;                      // pairs >= c
                if (r0)      dR = (float)__builtin_ctzll(r0) + 0.5f;
                else if (m1) dR = (float)(64 - c + __builtin_ctzll(m1)) + 0.5f;
                float d = fminf(dL, dR);                // in cell units
                float prox = hw_exp2(d * -0.5770780f);  // exp(-0.4 d)

                float sv = st_s[c];
                unsigned short shi = f2bf(sv);
                unsigned short slo = f2bf(sv - bf2f(shi));  // double-bf16 state
                feat_s[foff0] = shi;
                feat_s[foff1] = slo;
                feat_s[foff2] = f2bf(prox);
            }
        }
        __syncthreads();   // B: features ready

        // ---- L0 (1x MFMA bf16, K=32): feat x W0'^T -> actA ----
        {
            f32x4 c4 = {bias0, bias0, bias0, bias0};   // bias folded into C-init
            c4 = __builtin_amdgcn_mfma_f32_16x16x32_bf16(*prF, w0f, c4, 0, 0, 0);
            f32x2 g01 = pk_gelu((f32x2){c4[0], c4[1]});
            f32x2 g23 = pk_gelu((f32x2){c4[2], c4[3]});
            unsigned u01 = cvt_pk_bf16(g01.x, g01.y);
            unsigned u23 = cvt_pk_bf16(g23.x, g23.y);
            *pwA0 = (unsigned short)u01;
            *pwA1 = (unsigned short)(u01 >> 16);
            *pwA2 = (unsigned short)u23;
            *pwA3 = (unsigned short)(u23 >> 16);
        }
        __syncthreads();   // C: actA ready

        // ---- L1 (MFMA bf16, K=64): actA x W1^T -> actB ----
        {
            f32x4 c4 = {bias1, bias1, bias1, bias1};
            c4 = __builtin_amdgcn_mfma_f32_16x16x32_bf16(*prA0, w1fa, c4, 0, 0, 0);
            c4 = __builtin_amdgcn_mfma_f32_16x16x32_bf16(*prA1, w1fb, c4, 0, 0, 0);
            f32x2 g01 = pk_gelu((f32x2){c4[0], c4[1]});
            f32x2 g23 = pk_gelu((f32x2){c4[2], c4[3]});
            unsigned u01 = cvt_pk_bf16(g01.x, g01.y);
            unsigned u23 = cvt_pk_bf16(g23.x, g23.y);
            *pwB0 = (unsigned short)u01;
            *pwB1 = (unsigned short)(u01 >> 16);
            *pwB2 = (unsigned short)u23;
            *pwB3 = (unsigned short)(u23 >> 16);
        }
        __syncthreads();   // D: actB ready

        // ---- L2 (MFMA bf16) + fused L3 partial (2-stage shfl -> 16/row) ----
        {
            f32x4 c4 = {bias2, bias2, bias2, bias2};
            c4 = __builtin_amdgcn_mfma_f32_16x16x32_bf16(*prB0, w2fa, c4, 0, 0, 0);
            c4 = __builtin_amdgcn_mfma_f32_16x16x32_bf16(*prB1, w2fb, c4, 0, 0, 0);
            f32x2 g01 = pk_gelu((f32x2){c4[0], c4[1]});
            f32x2 g23 = pk_gelu((f32x2){c4[2], c4[3]});
            float pj0 = w3c * g01.x, pj1 = w3c * g01.y;
            float pj2 = w3c * g23.x, pj3 = w3c * g23.y;
            {
                float p = pj0;
                p += __shfl_xor(p, 1); p += __shfl_xor(p, 2);
                if (pwrite) part_s[poff] = p;
            }
            {
                float p = pj1;
                p += __shfl_xor(p, 1); p += __shfl_xor(p, 2);
                if (pwrite) part_s[poff + 20] = p;
            }
            {
                float p = pj2;
                p += __shfl_xor(p, 1); p += __shfl_xor(p, 2);
                if (pwrite) part_s[poff + 40] = p;
            }
            {
                float p = pj3;
                p += __shfl_xor(p, 1); p += __shfl_xor(p, 2);
                if (pwrite) part_s[poff + 60] = p;
            }
        }
        __syncthreads();   // E: partials ready

        // ---- E->A window: wave0 update+publish  ||  wave1 poll row t halo ----
        // Disjoint st_s regions: wave0 writes [32..47]; wave1 writes [0..31],
        // [64..79]. Edge blocks' clamped lanes self-poll the word wave0 is
        // publishing in this same window — wave0 never waits on wave1 (live).
        if (wid == 0 && lane < 16) {
            f32x4 s4 = pru[0] + pru[1] + pru[2] + pru[3];
            float sum = s4[0] + s4[1] + s4[2] + s4[3];
            float ns = st_s[32 + l15] + r * (sum + b3v);
            ns = fminf(1.0f, fmaxf(0.0f, ns));
            if (t < NT - 1) {
                u64t u = ((u64t)(unsigned)t << 32) |
                         (u64t)(unsigned)__builtin_bit_cast(unsigned, ns);
                sys_store_u64(hpub + (size_t)((t & 3) * 16), u);
            }
            ocell[(size_t)t * NX] = ns;
            st_s[32 + l15] = ns;
        } else if (wid == 1 && t < NT - 1) {
            // fill strip halo with row t from neighbors (fused data+tag/lane);
            // consumed by next iteration's feature phase after barrier A
            const unsigned need = (unsigned)t;
            const u64t* src = hbase + (size_t)((t & 3) * 16);
            u64t u;
            do { u = sys_load_u64(src); } while ((unsigned)(u >> 32) < need);
            st_s[hdst] = __builtin_bit_cast(float, (unsigned)u);
        }
        __syncthreads();   // A: strip now holds row t (+ halo); next iteration
    }
}

extern "C" void kernel_launch(void* const* d_in, const int* in_sizes, int n_in,
                              void* d_out, int out_size, void* d_ws, size_t ws_size,
                              hipStream_t stream) {
    const float* grid = (const float*)d_in[0];
    const float* dtp  = (const float*)d_in[1];
    const float* W0   = (const float*)d_in[2];
    const float* b0   = (const float*)d_in[3];
    const float* W1   = (const float*)d_in[4];
    const float* b1   = (const float*)d_in[5];
    const float* W2   = (const float*)d_in[6];
    const float* b2   = (const float*)d_in[7];
    const float* W3   = (const float*)d_in[8];
    const float* b3   = (const float*)d_in[9];
    float* outp = (float*)d_out;

    u64t* halo = (u64t*)d_ws;                     // NBLK * 64 u64 (512 KB)

    // zero the whole mailbox each launch: tags embedded in data words must
    // not leak across graph replays (stale tag >= need hands out old rows)
    hipMemsetAsync(d_ws, 0, (size_t)NBLK * 64 * sizeof(u64t), stream);

    void* args[] = {(void*)&grid, (void*)&dtp, (void*)&W0, (void*)&b0,
                    (void*)&W1, (void*)&b1, (void*)&W2, (void*)&b2,
                    (void*)&W3, (void*)&b3, (void*)&outp, (void*)&halo};

    // Deterministic launch-mode choice (query enqueues nothing; capture-safe).
    // Coop launch caps grid at occupancy*256; need >=4 blocks/CU for 1024.
    // Fallback plain launch: all 1024 blocks fit simultaneously (8KB LDS,
    // 256 thr, VGPR bounded) -> spins stay live.
    int maxb = 0;
    hipError_t qe = hipOccupancyMaxActiveBlocksPerMultiprocessor(
        &maxb, (const void*)nfv_kernel, 256, 0);
    if (qe == hipSuccess && maxb >= 4) {
        hipLaunchCooperativeKernel((const void*)nfv_kernel,
                                   dim3(NBLK), dim3(256), args, 0, stream);
    } else {
        hipLaunchKernelGGL(nfv_kernel, dim3(NBLK), dim3(256), 0, stream,
                           grid, dtp, W0, b0, W1, b1, W2, b2, W3, b3,
                           outp, halo);
    }
}